// Round 12
// baseline (398.888 us; speedup 1.0000x reference)
//
#include <hip/hip_runtime.h>
#include <math.h>

#define E 256
#define SEQ 32
#define FF 1024
#define NEG_MASK -10000.0f

typedef __attribute__((ext_vector_type(8))) short bf16x8;
typedef __attribute__((ext_vector_type(4))) short s16x4;
typedef __attribute__((ext_vector_type(4))) float f32x4;
typedef __attribute__((ext_vector_type(16))) float f32x16;

__device__ __forceinline__ float bf2f(unsigned short u) {
  unsigned v = ((unsigned)u) << 16; float f; __builtin_memcpy(&f, &v, 4); return f;
}
__device__ __forceinline__ unsigned short f2bf(float f) {
  unsigned u; __builtin_memcpy(&u, &f, 4);
  unsigned r = (u + 0x7fffu + ((u >> 16) & 1u)) >> 16;
  return (unsigned short)r;
}
__device__ __forceinline__ s16x4 f2bf4(float4 v) {
  s16x4 r;
  r[0] = (short)f2bf(v.x); r[1] = (short)f2bf(v.y);
  r[2] = (short)f2bf(v.z); r[3] = (short)f2bf(v.w);
  return r;
}
__device__ __forceinline__ f32x4 mfma16(bf16x8 a, bf16x8 b, f32x4 c) {
  return __builtin_amdgcn_mfma_f32_16x16x32_bf16(a, b, c, 0, 0, 0);
}
__device__ __forceinline__ f32x16 mfma32(bf16x8 a, bf16x8 b, f32x16 c) {
  return __builtin_amdgcn_mfma_f32_32x32x16_bf16(a, b, c, 0, 0, 0);
}
__device__ __forceinline__ float block_sum256(float v, float* tmp4) {
  #pragma unroll
  for (int o = 32; o > 0; o >>= 1) v += __shfl_down(v, o);
  int wid = threadIdx.x >> 6, lane = threadIdx.x & 63;
  if (lane == 0) tmp4[wid] = v;
  __syncthreads();
  float r = tmp4[0] + tmp4[1] + tmp4[2] + tmp4[3];
  __syncthreads();
  return r;
}

// ---------------- weight prep: fp32 W[k][n] -> bf16 fragment-order swizzle ----------------
__global__ __launch_bounds__(256) void wprep_kernel(
    const float* __restrict__ Wq, const float* __restrict__ Wk,
    const float* __restrict__ Wv, const float* __restrict__ Wo,
    const float* __restrict__ Wi, const float* __restrict__ Wf,
    unsigned short* wqt, unsigned short* wkt, unsigned short* wvt,
    unsigned short* wot, unsigned short* wit, unsigned short* wft) {
  int type = blockIdx.y, ll = blockIdx.z, t = threadIdx.x;
  const float* src; unsigned short* dst; int Kd, Nd, m32;
  switch (type) {
    case 0: src = Wq + (size_t)ll * 65536;  dst = wqt + (size_t)ll * 65536;  Kd = 256;  Nd = 256;  m32 = 0; break;
    case 1: src = Wk + (size_t)ll * 65536;  dst = wkt + (size_t)ll * 65536;  Kd = 256;  Nd = 256;  m32 = 0; break;
    case 2: src = Wv + (size_t)ll * 65536;  dst = wvt + (size_t)ll * 65536;  Kd = 256;  Nd = 256;  m32 = 0; break;
    case 3: src = Wo + (size_t)ll * 65536;  dst = wot + (size_t)ll * 65536;  Kd = 256;  Nd = 256;  m32 = 0; break;
    case 4: src = Wi + (size_t)ll * 262144; dst = wit + (size_t)ll * 262144; Kd = 256;  Nd = 1024; m32 = 1; break;
    default: src = Wf + (size_t)ll * 262144; dst = wft + (size_t)ll * 262144; Kd = 1024; Nd = 256; m32 = 1; break;
  }
  int frag = blockIdx.x * 4 + (t >> 6);
  int l = t & 63;
  int nkc = m32 ? (Kd >> 4) : (Kd >> 5);
  int nfrag = (m32 ? (Nd >> 5) : (Nd >> 4)) * nkc;
  if (frag >= nfrag) return;
  int n, k0;
  if (m32) { n = (frag / nkc) * 32 + (l & 31); k0 = (frag % nkc) * 16 + (l >> 5) * 8; }
  else     { n = (frag / nkc) * 16 + (l & 15); k0 = (frag % nkc) * 32 + (l >> 4) * 8; }
  unsigned short vv[8];
  #pragma unroll
  for (int j = 0; j < 8; ++j) vv[j] = f2bf(src[(size_t)(k0 + j) * Nd + n]);
  unsigned short* o = dst + (size_t)frag * 512 + l * 8;
  #pragma unroll
  for (int j = 0; j < 8; ++j) o[j] = vv[j];
}

// ---------------- sparse prop + W_d + LN; grid (64, 2); lean LDS (34 KB) ----------------
__global__ __launch_bounds__(256) void prop_ln_kernel(
    const float* __restrict__ emb_q, const float* __restrict__ emb_k,
    const float* snq,
    const float* __restrict__ uop, const float* __restrict__ iop,
    const float* __restrict__ Wd1, const float* __restrict__ bd1,
    const float* __restrict__ g1v, const float* __restrict__ b1v,
    const float* __restrict__ Wd2, const float* __restrict__ bd2,
    const float* __restrict__ g2v, const float* __restrict__ b2v,
    float* __restrict__ out1, float* __restrict__ out2) {
  int sel = blockIdx.y;
  const float* emb = sel ? emb_k : emb_q;
  const float* op  = sel ? iop : uop;
  const float* Wd  = sel ? Wd2 : Wd1;
  const float* bd  = sel ? bd2 : bd1;
  const float* g   = sel ? g2v : g1v;
  const float* bvec= sel ? b2v : b1v;
  float* outp      = sel ? out2 : out1;
  int row = sel;
  __shared__ float s1[16 * E];
  __shared__ float s2[16 * E];
  __shared__ float wv[64];
  __shared__ int gi[64];
  __shared__ float t2row[E];
  __shared__ float tmp4[4];
  int b = blockIdx.x, e = threadIdx.x;
  if (e < 64) {
    wv[e] = op[(b * 64 + e) * 2 + 1];
    gi[e] = (int)op[(b * 64 + e) * 2 + 0];
  }
  for (int gg = 0; gg < 16; ++gg) { s1[gg * E + e] = 0.f; s2[gg * E + e] = 0.f; }
  __syncthreads();
  float t0r = 0.f;
  for (int n = 0; n < 64; ++n) {
    float t0 = 0.5f * emb[(size_t)(b * 64 + n) * E + e];
    if (snq) t0 += snq[((size_t)(b * 64 + n) * 2 + sel) * E + e];
    if (n == row) t0r = t0;
    s1[gi[n] * E + e] += wv[n] * t0;   // column-private: no races
  }
  for (int n = 0; n < 64; ++n) {
    float t0 = 0.5f * emb[(size_t)(b * 64 + n) * E + e];
    if (snq) t0 += snq[((size_t)(b * 64 + n) * 2 + sel) * E + e];
    float t1 = wv[n] * s1[gi[n] * E + e] + 0.1f * t0;
    s2[gi[n] * E + e] += wv[n] * t1;
  }
  float t2 = wv[row] * s2[gi[row] * E + e] + 0.1f * t0r;
  t2row[e] = t2;
  __syncthreads();
  float y = bd[e];
  for (int k = 0; k < E; ++k) y = fmaf(t2row[k], Wd[k * E + e], y);
  float ssum = block_sum256(y, tmp4);
  float qsum = block_sum256(y * y, tmp4);
  float m = ssum * (1.f / E);
  float var = qsum * (1.f / E) - m * m;
  outp[b * E + e] = (y - m) * rsqrtf(var + 1e-12f) * g[e] + bvec[e];
}

// ---------------- fused per-seq: K+Q proj, MFMA scores, softmax, V proj, PV ----------------
__global__ __launch_bounds__(256, 4) void seq_attn_mfma(
    const float* __restrict__ hidden,
    const unsigned short* __restrict__ wqt, const float* __restrict__ bq,
    const unsigned short* __restrict__ wkt, const float* __restrict__ bk,
    const unsigned short* __restrict__ wvt, const float* __restrict__ bv,
    const float* __restrict__ mask, unsigned short* __restrict__ ctx_all,
    unsigned short* __restrict__ Kf, unsigned short* __restrict__ Vf) {
  __shared__ __align__(16) unsigned short aT[32][264];
  __shared__ __align__(16) unsigned short kvb[32][272];
  __shared__ __align__(16) unsigned short qs16[2][264];
  __shared__ float pr[4][2][36];
  int a = blockIdx.x, t = threadIdx.x;
  int w = t >> 6, l = t & 63;
  int lm = l & 15, lkq = l >> 4, lk = lkq << 3;
  size_t hb = (size_t)a * (SEQ * E);
  #pragma unroll
  for (int i = 0; i < 8; ++i) {
    int p = i * 256 + t; int row = p >> 6, c4 = (p & 63) << 2;
    float4 v = *(const float4*)&hidden[hb + row * E + c4];
    *(s16x4*)&aT[row][c4] = f2bf4(v);
  }
  __syncthreads();
  bool isn0 = ((a & 63) == 0);
  int nb = a >> 6;
  f32x4 zz = {0.f, 0.f, 0.f, 0.f};
  #pragma unroll
  for (int nt = 0; nt < 4; ++nt) {
    int ncol = w * 64 + nt * 16 + lm;
    const unsigned short* bkrow = wkt + ((size_t)(w * 4 + nt) * 8) * 512 + l * 8;
    const unsigned short* bqrow = wqt + ((size_t)(w * 4 + nt) * 8) * 512 + l * 8;
    bf16x8 bk8[8], bq8[8];
    #pragma unroll
    for (int kc = 0; kc < 8; ++kc) bk8[kc] = *(const bf16x8*)(bkrow + kc * 512);
    #pragma unroll
    for (int kc = 0; kc < 8; ++kc) bq8[kc] = *(const bf16x8*)(bqrow + kc * 512);
    f32x4 ak0 = zz, ak1 = zz, aq = zz;
    #pragma unroll
    for (int kc = 0; kc < 8; ++kc) {
      bf16x8 a0 = *(const bf16x8*)&aT[lm][kc * 32 + lk];
      bf16x8 a1 = *(const bf16x8*)&aT[16 + lm][kc * 32 + lk];
      ak0 = mfma16(a0, bk8[kc], ak0);
      ak1 = mfma16(a1, bk8[kc], ak1);
      aq  = mfma16(a0, bq8[kc], aq);
    }
    float bb = bk[ncol];
    #pragma unroll
    for (int r = 0; r < 4; ++r) {
      int rw = (lkq << 2) + r;
      float v0 = ak0[r] + bb, v1 = ak1[r] + bb;
      kvb[rw][ncol] = f2bf(v0);
      kvb[16 + rw][ncol] = f2bf(v1);
      if (isn0) {
        Kf[((size_t)nb * 32 + rw) * 256 + ncol] = f2bf(v0);
        Kf[((size_t)nb * 32 + 16 + rw) * 256 + ncol] = f2bf(v1);
      }
    }
    if (lkq == 0) {
      float bqv = bq[ncol];
      qs16[0][ncol] = f2bf(aq[0] + bqv);
      qs16[1][ncol] = f2bf(aq[1] + bqv);
    }
  }
  __syncthreads();
  {
    f32x4 sc0 = zz, sc1 = zz;
    #pragma unroll
    for (int kc2 = 0; kc2 < 2; ++kc2) {
      bf16x8 aq = *(const bf16x8*)&qs16[lm & 1][w * 64 + kc2 * 32 + lk];
      bf16x8 b0 = *(const bf16x8*)&kvb[lm][w * 64 + kc2 * 32 + lk];
      bf16x8 b1 = *(const bf16x8*)&kvb[16 + lm][w * 64 + kc2 * 32 + lk];
      sc0 = mfma16(aq, b0, sc0);
      sc1 = mfma16(aq, b1, sc1);
    }
    float mv0 = (lm < 4) ? NEG_MASK : mask[(size_t)a * SEQ + lm];
    float mv1 = mask[(size_t)a * SEQ + 16 + lm];
    #pragma unroll
    for (int r = 0; r < 2; ++r) {
      float s0 = sc0[r] * 0.125f + mv0;
      float s1 = sc1[r] * 0.125f + mv1;
      float mx = fmaxf(s0, s1);
      mx = fmaxf(mx, __shfl_xor(mx, 1));
      mx = fmaxf(mx, __shfl_xor(mx, 2));
      mx = fmaxf(mx, __shfl_xor(mx, 4));
      mx = fmaxf(mx, __shfl_xor(mx, 8));
      float e0 = expf(s0 - mx), e1 = expf(s1 - mx);
      float se = e0 + e1;
      se += __shfl_xor(se, 1); se += __shfl_xor(se, 2);
      se += __shfl_xor(se, 4); se += __shfl_xor(se, 8);
      float inv = 1.f / se;
      if (lkq == 0) {
        pr[w][r][lm] = e0 * inv;
        pr[w][r][16 + lm] = e1 * inv;
      }
    }
  }
  __syncthreads();
  #pragma unroll
  for (int nt = 0; nt < 4; ++nt) {
    int ncol = w * 64 + nt * 16 + lm;
    const unsigned short* bvrow = wvt + ((size_t)(w * 4 + nt) * 8) * 512 + l * 8;
    bf16x8 bv8[8];
    #pragma unroll
    for (int kc = 0; kc < 8; ++kc) bv8[kc] = *(const bf16x8*)(bvrow + kc * 512);
    f32x4 av0 = zz, av1 = zz;
    #pragma unroll
    for (int kc = 0; kc < 8; ++kc) {
      bf16x8 a0 = *(const bf16x8*)&aT[lm][kc * 32 + lk];
      bf16x8 a1 = *(const bf16x8*)&aT[16 + lm][kc * 32 + lk];
      av0 = mfma16(a0, bv8[kc], av0);
      av1 = mfma16(a1, bv8[kc], av1);
    }
    float bb = bv[ncol];
    #pragma unroll
    for (int r = 0; r < 4; ++r) {
      int rw = (lkq << 2) + r;
      float v0 = av0[r] + bb, v1 = av1[r] + bb;
      kvb[rw][ncol] = f2bf(v0);
      kvb[16 + rw][ncol] = f2bf(v1);
      if (isn0) {
        Vf[((size_t)nb * 32 + rw) * 256 + ncol] = f2bf(v0);
        Vf[((size_t)nb * 32 + 16 + rw) * 256 + ncol] = f2bf(v1);
      }
    }
  }
  __syncthreads();
  {
    float o0 = 0.f, o1 = 0.f;
    #pragma unroll
    for (int tt = 0; tt < 32; ++tt) {
      float vv = bf2f(kvb[tt][t]);
      o0 = fmaf(pr[w][0][tt], vv, o0);
      o1 = fmaf(pr[w][1][tt], vv, o1);
    }
    ctx_all[((size_t)a * 2 + 0) * E + t] = f2bf(o0);
    ctx_all[((size_t)a * 2 + 1) * E + t] = f2bf(o1);
  }
}

// ---------------- Q projection for n0 rows (gathered A), swizzled B ----------------
__global__ __launch_bounds__(256) void gemm_bias_kernel(
    const float* __restrict__ Af, const unsigned short* __restrict__ Bt,
    const float* __restrict__ bias, unsigned short* __restrict__ outb) {
  __shared__ __align__(16) unsigned short aT[32][264];
  int t = threadIdx.x, w = t >> 6, l = t & 63;
  int lm = l & 15, lkq = l >> 4, lk = lkq << 3;
  int row0 = blockIdx.x * 32;
  #pragma unroll
  for (int i = 0; i < 8; ++i) {
    int p = i * 256 + t; int row = p >> 6, c4 = (p & 63) << 2;
    int gr = row0 + row;
    int src = ((gr >> 5) << 11) + (gr & 31);
    float4 v = *(const float4*)&Af[(size_t)src * E + c4];
    *(s16x4*)&aT[row][c4] = f2bf4(v);
  }
  __syncthreads();
  f32x4 zz = {0.f, 0.f, 0.f, 0.f};
  #pragma unroll
  for (int nt = 0; nt < 4; ++nt) {
    int ncol = w * 64 + nt * 16 + lm;
    const unsigned short* brow = Bt + ((size_t)(w * 4 + nt) * 8) * 512 + l * 8;
    bf16x8 b8[8];
    #pragma unroll
    for (int kc = 0; kc < 8; ++kc) b8[kc] = *(const bf16x8*)(brow + kc * 512);
    f32x4 c0 = zz, c1 = zz;
    #pragma unroll
    for (int kc = 0; kc < 8; ++kc) {
      bf16x8 a0 = *(const bf16x8*)&aT[lm][kc * 32 + lk];
      bf16x8 a1 = *(const bf16x8*)&aT[16 + lm][kc * 32 + lk];
      c0 = mfma16(a0, b8[kc], c0);
      c1 = mfma16(a1, b8[kc], c1);
    }
    float bb = bias[ncol];
    #pragma unroll
    for (int r = 0; r < 4; ++r) {
      int rw = (lkq << 2) + r;
      outb[(size_t)(row0 + rw) * E + ncol] = f2bf(c0[r] + bb);
      outb[(size_t)(row0 + 16 + rw) * E + ncol] = f2bf(c1[r] + bb);
    }
  }
}

// ---------------- iter-1 QKV: grid (seq, matrix) ----------------
__global__ __launch_bounds__(256) void qkv1_kernel(
    const unsigned short* __restrict__ Ab,
    const unsigned short* __restrict__ wq, const float* __restrict__ bqv,
    const unsigned short* __restrict__ wk, const float* __restrict__ bkv,
    const unsigned short* __restrict__ wv, const float* __restrict__ bvv,
    unsigned short* q2, unsigned short* k2, unsigned short* v2) {
  __shared__ __align__(16) unsigned short aT[32][264];
  int t = threadIdx.x, w = t >> 6, l = t & 63;
  int lm = l & 15, lkq = l >> 4, lk = lkq << 3;
  int row0 = blockIdx.x * 32;
  int m = blockIdx.y;
  const unsigned short* Wt = (m == 0) ? wq : (m == 1) ? wk : wv;
  const float* bb = (m == 0) ? bqv : (m == 1) ? bkv : bvv;
  unsigned short* outb = (m == 0) ? q2 : (m == 1) ? k2 : v2;
  #pragma unroll
  for (int i = 0; i < 4; ++i) {
    int p = i * 256 + t; int row = p >> 5, c8 = (p & 31) << 3;
    *(s16x4*)&aT[row][c8] = *(const s16x4*)&Ab[(size_t)(row0 + row) * E + c8];
    *(s16x4*)&aT[row][c8 + 4] = *(const s16x4*)&Ab[(size_t)(row0 + row) * E + c8 + 4];
  }
  __syncthreads();
  f32x4 zz = {0.f, 0.f, 0.f, 0.f};
  #pragma unroll
  for (int nt = 0; nt < 4; ++nt) {
    int ncol = w * 64 + nt * 16 + lm;
    const unsigned short* brow = Wt + ((size_t)(w * 4 + nt) * 8) * 512 + l * 8;
    bf16x8 b8[8];
    #pragma unroll
    for (int kc = 0; kc < 8; ++kc) b8[kc] = *(const bf16x8*)(brow + kc * 512);
    f32x4 c0 = zz, c1 = zz;
    #pragma unroll
    for (int kc = 0; kc < 8; ++kc) {
      bf16x8 a0 = *(const bf16x8*)&aT[lm][kc * 32 + lk];
      bf16x8 a1 = *(const bf16x8*)&aT[16 + lm][kc * 32 + lk];
      c0 = mfma16(a0, b8[kc], c0);
      c1 = mfma16(a1, b8[kc], c1);
    }
    float bv2 = bb[ncol];
    #pragma unroll
    for (int r = 0; r < 4; ++r) {
      int rw = (lkq << 2) + r;
      outb[(size_t)(row0 + rw) * E + ncol] = f2bf(c0[r] + bv2);
      outb[(size_t)(row0 + 16 + rw) * E + ncol] = f2bf(c1[r] + bv2);
    }
  }
}

// ---------------- full attention (bf16 in/out), compact 64-seq buffers ----------------
__global__ __launch_bounds__(256) void attnf_kernel(
    const unsigned short* __restrict__ Q, const unsigned short* __restrict__ K,
    const unsigned short* __restrict__ V, unsigned short* __restrict__ CTX,
    const float* __restrict__ mask, int set4) {
  int b = blockIdx.x, h = blockIdx.y, t = threadIdx.x;
  __shared__ float qsh[32][65], ksh[32][65], vsh[32][65];
  __shared__ float pr[32][33];
  size_t base = (size_t)b * (SEQ * E) + h * 64;
  for (int i = 0; i < 8; ++i) {
    int p = i * 256 + t; int s = p >> 6, d = p & 63;
    qsh[s][d] = bf2f(Q[base + s * E + d]);
    ksh[s][d] = bf2f(K[base + s * E + d]);
    vsh[s][d] = bf2f(V[base + s * E + d]);
  }
  __syncthreads();
  for (int i = 0; i < 4; ++i) {
    int p = i * 256 + t; int s = p >> 5, tt = p & 31;
    float acc = 0.f;
    #pragma unroll
    for (int d = 0; d < 64; ++d) acc = fmaf(qsh[s][d], ksh[tt][d], acc);
    float mv = mask[(size_t)b * 2048 + tt];
    if (set4 && tt < 4) mv = NEG_MASK;
    pr[s][tt] = acc * 0.125f + mv;
  }
  __syncthreads();
  int rrow = t >> 3, l8 = t & 7;
  float vals[4];
  float mx = -1e30f;
  #pragma unroll
  for (int ii = 0; ii < 4; ++ii) { vals[ii] = pr[rrow][l8 + ii * 8]; mx = fmaxf(mx, vals[ii]); }
  mx = fmaxf(mx, __shfl_xor(mx, 1));
  mx = fmaxf(mx, __shfl_xor(mx, 2));
  mx = fmaxf(mx, __shfl_xor(mx, 4));
  float se = 0.f;
  #pragma unroll
  for (int ii = 0; ii < 4; ++ii) { vals[ii] = expf(vals[ii] - mx); se += vals[ii]; }
  se += __shfl_xor(se, 1); se += __shfl_xor(se, 2); se += __shfl_xor(se, 4);
  float inv = 1.f / se;
  #pragma unroll
  for (int ii = 0; ii < 4; ++ii) pr[rrow][l8 + ii * 8] = vals[ii] * inv;
  __syncthreads();
  for (int i = 0; i < 8; ++i) {
    int p = i * 256 + t; int s = p >> 6, d = p & 63;
    float acc = 0.f;
    #pragma unroll
    for (int tt = 0; tt < SEQ; ++tt) acc = fmaf(pr[s][tt], vsh[tt][d], acc);
    CTX[base + s * E + d] = f2bf(acc);
  }
}

__device__ __forceinline__ int map_res(int gr) {
  if (gr < 8192) return ((gr >> 1) << 5) + (gr & 1);
  int rr = gr - 8192;
  return ((rr >> 5) << 11) + (rr & 31);
}

// ---------------- fused ffnB: Wo GEMM + LN1 (redundant per qh) + FF-quarter GEMM1+gelu+partial GEMM2 ----------------
// 512 threads. qh==0 blocks also write the fp32 LN1 output (ffnC residual).
__global__ __launch_bounds__(512) void ffnB_kernel(
    const unsigned short* __restrict__ ctx,
    const unsigned short* __restrict__ wo, const float* __restrict__ bo,
    const float* __restrict__ Res, int resmode,
    const float* __restrict__ g1, const float* __restrict__ b1,
    const unsigned short* __restrict__ wi, const float* __restrict__ bi,
    const unsigned short* __restrict__ wf,
    float* __restrict__ a_f32, unsigned short* __restrict__ part, size_t pstride) {
  __shared__ __align__(16) char smem[16896 + 32896];
  unsigned short (*aT)[264] = (unsigned short(*)[264])smem;            // ctx, then LN1 bf16
  float (*sT)[257] = (float(*)[257])(smem + 16896);                    // Wo+res accum (fp32)
  unsigned short (*fT)[264] = (unsigned short(*)[264])(smem + 16896);  // aliases sT after LN1
  __shared__ float prs[32][4], prq[32][4];
  int t = threadIdx.x, w = t >> 6, l = t & 63;
  int row0 = blockIdx.x * 32, qh = blockIdx.y;
  // stage ctx -> aT (512 threads: 4 chunks)
  #pragma unroll
  for (int i = 0; i < 4; ++i) {
    int p = i * 512 + t; int row = p >> 6, c4 = (p & 63) << 2;
    *(s16x4*)&aT[row][c4] = *(const s16x4*)&ctx[(size_t)(row0 + row) * E + c4];
  }
  __syncthreads();
  // Wo GEMM (mfma16, 8 waves x 2 n-tiles) -> sT = acc + bo + residual
  {
    int lm = l & 15, lkq = l >> 4, lk = lkq << 3;
    f32x4 zz = {0.f, 0.f, 0.f, 0.f};
    #pragma unroll
    for (int nt = 0; nt < 2; ++nt) {
      int ncol = w * 32 + nt * 16 + lm;
      const unsigned short* brow = wo + ((size_t)(w * 2 + nt) * 8) * 512 + l * 8;
      bf16x8 b8[8];
      #pragma unroll
      for (int kc = 0; kc < 8; ++kc) b8[kc] = *(const bf16x8*)(brow + kc * 512);
      f32x4 c0 = zz, c1 = zz;
      #pragma unroll
      for (int kc = 0; kc < 8; ++kc) {
        bf16x8 a0 = *(const bf16x8*)&aT[lm][kc * 32 + lk];
        bf16x8 a1 = *(const bf16x8*)&aT[16 + lm][kc * 32 + lk];
        c0 = mfma16(a0, b8[kc], c0);
        c1 = mfma16(a1, b8[kc], c1);
      }
      float bb = bo[ncol];
      #pragma unroll
      for (int r = 0; r < 4; ++r) {
        int rw = (lkq << 2) + r;
        int rr0 = resmode ? map_res(row0 + rw) : (row0 + rw);
        int rr1 = resmode ? map_res(row0 + 16 + rw) : (row0 + 16 + rw);
        sT[rw][ncol] = c0[r] + bb + Res[(size_t)rr0 * E + ncol];
        sT[16 + rw][ncol] = c1[r] + bb + Res[(size_t)rr1 * E + ncol];
      }
    }
  }
  __syncthreads();
  // LN1 (threads t<256; col = t) -> aT bf16 (+ a_f32 from qh==0)
  {
    int wid = t >> 6, lane = t & 63;
    float vcache[32];
    if (t < 256) {
      for (int r = 0; r < 32; ++r) {
        float v = sT[r][t];
        vcache[r] = v;
        float s = v, q = v * v;
        #pragma unroll
        for (int o = 32; o > 0; o >>= 1) { s += __shfl_down(s, o); q += __shfl_down(q, o); }
        if (lane == 0) { prs[r][wid] = s; prq[r][wid] = q; }
      }
    }
    __syncthreads();
    if (t < 256) {
      #pragma unroll
      for (int r = 0; r < 32; ++r) {
        float Sv = prs[r][0] + prs[r][1] + prs[r][2] + prs[r][3];
        float Qv = prq[r][0] + prq[r][1] + prq[r][2] + prq[r][3];
        float m = Sv * (1.f / E), var = Qv * (1.f / E) - m * m;
        float val = (vcache[r] - m) * rsqrtf(var + 1e-12f) * g1[t] + b1[t];
        aT[r][t] = f2bf(val);
        if (qh == 0) a_f32[(size_t)(row0 + r) * E + t] = val;
      }
    }
    __syncthreads();   // all sT reads done; fT (aliasing sT) now writable; aT ready
  }
  int lm = l & 31, lk = (l >> 5) << 3;
  f32x16 zz16 = {0};
  // GEMM1: FF cols qh*256 + w*32 + lm, gelu -> fT
  {
    const unsigned short* brow = wi + ((size_t)(qh * 8 + w) * 16) * 512 + l * 8;
    bf16x8 b16[16];
    #pragma unroll
    for (int kc = 0; kc < 16; ++kc) b16[kc] = *(const bf16x8*)(brow + kc * 512);
    f32x16 c = zz16;
    #pragma unroll
    for (int kc = 0; kc < 16; ++kc) {
      bf16x8 a = *(const bf16x8*)&aT[lm][kc * 16 + lk];
      c = mfma32(a, b16[kc], c);
    }
    int lcol = w * 32 + lm;
    float bib = bi[qh * 256 + lcol];
    #pragma unroll
    for (int reg = 0; reg < 16; ++reg) {
      int row = (reg & 3) + 8 * (reg >> 2) + 4 * (l >> 5);
      float x = c[reg] + bib;
      fT[row][lcol] = f2bf(0.5f * x * (1.f + erff(x * 0.70710678118654752f)));
    }
  }
  __syncthreads();
  // GEMM2 partial: out cols w*32 + lm, K = this quarter (256 of FF)
  {
    const unsigned short* brow = wf + ((size_t)(w * 64 + qh * 16)) * 512 + l * 8;
    bf16x8 b16[16];
    #pragma unroll
    for (int kc = 0; kc < 16; ++kc) b16[kc] = *(const bf16x8*)(brow + kc * 512);
    f32x16 c = zz16;
    #pragma unroll
    for (int kc = 0; kc < 16; ++kc) {
      bf16x8 a = *(const bf16x8*)&fT[lm][kc * 16 + lk];
      c = mfma32(a, b16[kc], c);
    }
    unsigned short* po = part + (size_t)qh * pstride;
    int col = w * 32 + lm;
    #pragma unroll
    for (int reg = 0; reg < 16; ++reg) {
      int row = (reg & 3) + 8 * (reg >> 2) + 4 * (l >> 5);
      po[(size_t)(row0 + row) * E + col] = f2bf(c[reg]);
    }
  }
}

// ---------------- ffnC: sum 4 bf16 partials + bias + residual + LN2 ----------------
__global__ __launch_bounds__(256) void ffnC_kernel(
    const unsigned short* __restrict__ part, size_t pstride,
    const float* __restrict__ bfv, const float* __restrict__ a_f32,
    const float* __restrict__ g2, const float* __restrict__ b2,
    float* __restrict__ out0, float* __restrict__ out1, int split) {
  __shared__ float prs[32][4], prq[32][4];
  int t = threadIdx.x;
  int row0 = blockIdx.x * 32;
  int wid = t >> 6, lane = t & 63;
  float bb = bfv[t];
  float vcache[32];
  for (int r = 0; r < 32; ++r) {
    size_t idx = (size_t)(row0 + r) * E + t;
    float v = bf2f(part[idx]) + bf2f(part[pstride + idx]) +
              bf2f(part[2 * pstride + idx]) + bf2f(part[3 * pstride + idx]) +
              bb + a_f32[idx];
    vcache[r] = v;
    float s = v, q = v * v;
    #pragma unroll
    for (int o = 32; o > 0; o >>= 1) { s += __shfl_down(s, o); q += __shfl_down(q, o); }
    if (lane == 0) { prs[r][wid] = s; prq[r][wid] = q; }
  }
  __syncthreads();
  #pragma unroll
  for (int r = 0; r < 32; ++r) {
    float Sv = prs[r][0] + prs[r][1] + prs[r][2] + prs[r][3];
    float Qv = prq[r][0] + prq[r][1] + prq[r][2] + prq[r][3];
    float m = Sv * (1.f / E), var = Qv * (1.f / E) - m * m;
    float val = (vcache[r] - m) * rsqrtf(var + 1e-12f) * g2[t] + b2[t];
    int gr = row0 + r;
    if (gr < split) out0[(size_t)gr * E + t] = val;
    else            out1[(size_t)(gr - split) * E + t] = val;
  }
}

// ---------------- fused agg (iter0) + build iter-1 input ----------------
__global__ __launch_bounds__(256) void agg_build_kernel(
    const float* __restrict__ h1n0,
    const float* __restrict__ p1, const float* __restrict__ p2,
    const float* __restrict__ Wagg, const float* __restrict__ bagg,
    const float* __restrict__ qe, const float* __restrict__ ke,
    const float* __restrict__ de, const float* __restrict__ ce,
    float* __restrict__ agg0,
    float* __restrict__ h2f, unsigned short* __restrict__ h2b) {
  __shared__ float pv[768];
  __shared__ float tmp4[4];
  int b = blockIdx.x, t = threadIdx.x;
  float x = h1n0[(size_t)b * (SEQ * E) + 4 * E + t];
  float n2 = block_sum256(x * x, tmp4);
  pv[t] = x / fmaxf(sqrtf(n2), 1e-12f);
  pv[256 + t] = p1[b * E + t];
  pv[512 + t] = p2[b * E + t];
  __syncthreads();
  float y = bagg[t];
  for (int u = 0; u < 768; ++u) y = fmaf(pv[u], Wagg[u * E + t], y);
  y = fmaxf(y, 0.f);
  float n3 = block_sum256(y * y, tmp4);
  float aggv = y / fmaxf(sqrtf(n3), 1e-12f);
  agg0[b * E + t] = aggv;
  size_t eb = (size_t)(b * 64) * E + t;
  size_t ob = (size_t)b * (SEQ * E);
  float v;
  v = qe[eb];  h2f[ob + 0 * E + t] = v; h2b[ob + 0 * E + t] = f2bf(v);
  v = ke[eb];  h2f[ob + 1 * E + t] = v; h2b[ob + 1 * E + t] = f2bf(v);
  v = de[eb];  h2f[ob + 2 * E + t] = v; h2b[ob + 2 * E + t] = f2bf(v);
  v = ce[eb];  h2f[ob + 3 * E + t] = v; h2b[ob + 3 * E + t] = f2bf(v);
  h2f[ob + 4 * E + t] = aggv; h2b[ob + 4 * E + t] = f2bf(aggv);
  for (int s = 5; s < SEQ; ++s) {
    v = h1n0[ob + s * E + t];
    h2f[ob + s * E + t] = v; h2b[ob + s * E + t] = f2bf(v);
  }
}

// ---------------- fused agg (iter1) + final output ----------------
__global__ __launch_bounds__(256) void agg_out_kernel(
    const float* __restrict__ h2,
    const float* __restrict__ p1, const float* __restrict__ p2,
    const float* __restrict__ Wagg, const float* __restrict__ bagg,
    const float* __restrict__ h1n0, const float* __restrict__ agg0,
    float* __restrict__ outp) {
  __shared__ float pv[768];
  __shared__ float tmp4[4];
  int b = blockIdx.x, t = threadIdx.x;
  float x = h2[(size_t)b * (SEQ * E) + 4 * E + t];
  float n2 = block_sum256(x * x, tmp4);
  pv[t] = x / fmaxf(sqrtf(n2), 1e-12f);
  pv[256 + t] = p1[b * E + t];
  pv[512 + t] = p2[b * E + t];
  __syncthreads();
  float y = bagg[t];
  for (int u = 0; u < 768; ++u) y = fmaf(pv[u], Wagg[u * E + t], y);
  y = fmaxf(y, 0.f);
  float n3 = block_sum256(y * y, tmp4);
  float agg1v = y / fmaxf(sqrtf(n3), 1e-12f);
  size_t ob = (size_t)b * (SEQ * E);
  float s1v = agg0[b * E + t];
  float s2v = agg1v;
  for (int s = 5; s < SEQ; ++s) { s1v += h1n0[ob + s * E + t]; s2v += h2[ob + s * E + t]; }
  outp[b * E + t] = 0.5f * (s1v + s2v) * (1.f / 28.f);
}

extern "C" void kernel_launch(void* const* d_in, const int* in_sizes, int n_in,
                              void* d_out, int out_size, void* d_ws, size_t ws_size,
                              hipStream_t stream) {
  (void)in_sizes; (void)n_in; (void)out_size;
  const float* hidden = (const float*)d_in[1];
  const float* amask  = (const float*)d_in[2];
  const float* qemb   = (const float*)d_in[3];
  const float* kemb   = (const float*)d_in[4];
  const float* demb   = (const float*)d_in[5];
  const float* cemb   = (const float*)d_in[6];
  const float* uop    = (const float*)d_in[7];
  const float* iop    = (const float*)d_in[8];
  const float* Wq = (const float*)d_in[9];  const float* bq = (const float*)d_in[10];
  const float* Wk = (const float*)d_in[11]; const float* bk = (const float*)d_in[12];
  const float* Wv = (const float*)d_in[13]; const float* bv = (const float*)d_in[14];
  const float* Wo = (const float*)d_in[15]; const float* bo = (const float*)d_in[16];
  const float* g1 = (const float*)d_in[17]; const float* b1 = (const float*)d_in[18];
  const float* Wi = (const float*)d_in[19]; const float* bi = (const float*)d_in[20];
  const float* Wf = (const float*)d_in[21]; const float* bf = (const float*)d_in[22];
  const float* g2 = (const float*)d_in[23]; const float* b2 = (const float*)d_in[24];
  const float* Wagg = (const float*)d_in[25]; const float* bagg = (const float*)d_in[26];
  const float* Wd1 = (const float*)d_in[27]; const float* bd1 = (const float*)d_in[28];
  const float* l1g = (const float*)d_in[29]; const float* l1b = (const float*)d_in[30];
  const float* Wd2 = (const float*)d_in[31]; const float* bd2 = (const float*)d_in[32];
  const float* l2g = (const float*)d_in[33]; const float* l2b = (const float*)d_in[34];

  // ---- workspace carve ----
  char* cur = (char*)d_ws;
  auto alloc_us = [&](size_t n) { unsigned short* p = (unsigned short*)cur; cur += ((n * 2 + 255) & ~(size_t)255); return p; };
  auto alloc_f  = [&](size_t n) { float* p = (float*)cur; cur += ((n * 4 + 255) & ~(size_t)255); return p; };
  unsigned short* wqt = alloc_us(131072);
  unsigned short* wkt = alloc_us(131072);
  unsigned short* wvt = alloc_us(131072);
  unsigned short* wot = alloc_us(131072);
  unsigned short* wit = alloc_us(524288);
  unsigned short* wft = alloc_us(524288);
  unsigned short* ctx_all = alloc_us((size_t)10240 * 256);
  unsigned short* qn0 = alloc_us((size_t)2048 * 256);
  unsigned short* Kf  = alloc_us((size_t)2048 * 256);
  unsigned short* Vf  = alloc_us((size_t)2048 * 256);
  unsigned short* h2inb = alloc_us((size_t)2048 * 256);
  unsigned short* q2b = alloc_us((size_t)2048 * 256);
  unsigned short* k2b = alloc_us((size_t)2048 * 256);
  unsigned short* v2b = alloc_us((size_t)2048 * 256);
  unsigned short* ctx1 = alloc_us((size_t)2048 * 256);
  unsigned short* part = alloc_us((size_t)4 * 10240 * 256);
  float* a_f32 = alloc_f((size_t)10240 * 256);
  float* h101  = alloc_f((size_t)4096 * 2 * 256);
  float* h1n0  = alloc_f((size_t)2048 * 256);
  float* h2inf = alloc_f((size_t)2048 * 256);
  float* h2    = alloc_f((size_t)2048 * 256);
  float* p1_0  = alloc_f(64 * 256);
  float* p2_0  = alloc_f(64 * 256);
  float* p1_1  = alloc_f(64 * 256);
  float* p2_1  = alloc_f(64 * 256);
  float* agg0  = alloc_f(64 * 256);
  if ((size_t)(cur - (char*)d_ws) > ws_size) return;
  const size_t PSTRIDE = (size_t)10240 * 256;

  // ---- weight prep (fragment-order swizzle) ----
  wprep_kernel<<<dim3(128, 6, 2), 256, 0, stream>>>(Wq, Wk, Wv, Wo, Wi, Wf,
                                                    wqt, wkt, wvt, wot, wit, wft);

  // ================= iteration 0 =================
  prop_ln_kernel<<<dim3(64, 2), 256, 0, stream>>>(qemb, kemb, nullptr, uop, iop,
                                                  Wd1, bd1, l1g, l1b, Wd2, bd2, l2g, l2b,
                                                  p1_0, p2_0);
  seq_attn_mfma<<<4096, 256, 0, stream>>>(hidden, wqt, bq, wkt, bk, wvt, bv,
                                          amask, ctx_all, Kf, Vf);
  gemm_bias_kernel<<<64, 256, 0, stream>>>(hidden, wqt, bq, qn0);
  attnf_kernel<<<dim3(64, 4), 256, 0, stream>>>(qn0, Kf, Vf, ctx_all + (size_t)8192 * 256,
                                                amask, 1);
  ffnB_kernel<<<dim3(320, 4), 512, 0, stream>>>(ctx_all, wot, bo, hidden, 1, g1, b1,
                                                wit, bi, wft, a_f32, part, PSTRIDE);
  ffnC_kernel<<<320, 256, 0, stream>>>(part, PSTRIDE, bf, a_f32, g2, b2,
                                       h101, h1n0, 8192);
  agg_build_kernel<<<64, 256, 0, stream>>>(h1n0, p1_0, p2_0, Wagg, bagg,
                                           qemb, kemb, demb, cemb, agg0, h2inf, h2inb);

  // ================= iteration 1 =================
  prop_ln_kernel<<<dim3(64, 2), 256, 0, stream>>>(qemb, kemb, h101, uop, iop,
                                                  Wd1, bd1, l1g, l1b, Wd2, bd2, l2g, l2b,
                                                  p1_1, p2_1);
  qkv1_kernel<<<dim3(64, 3), 256, 0, stream>>>(h2inb,
                                               wqt + 65536, bq + E,
                                               wkt + 65536, bk + E,
                                               wvt + 65536, bv + E,
                                               q2b, k2b, v2b);
  attnf_kernel<<<dim3(64, 4), 256, 0, stream>>>(q2b, k2b, v2b, ctx1, amask, 0);
  ffnB_kernel<<<dim3(64, 4), 512, 0, stream>>>(ctx1, wot + 65536, bo + E, h2inf, 0,
                                               g1 + E, b1 + E,
                                               wit + 262144, bi + FF, wft + 262144,
                                               a_f32, part, PSTRIDE);
  ffnC_kernel<<<64, 256, 0, stream>>>(part, PSTRIDE, bf + E, a_f32,
                                      g2 + E, b2 + E, h2, h2, 1 << 30);
  agg_out_kernel<<<64, 256, 0, stream>>>(h2, p1_1, p2_1,
                                         Wagg + (size_t)768 * E, bagg + E,
                                         h1n0, agg0, (float*)d_out);
}

// Round 13
// 383.346 us; speedup vs baseline: 1.0405x; 1.0405x over previous
//
#include <hip/hip_runtime.h>
#include <math.h>

#define E 256
#define SEQ 32
#define FF 1024
#define NEG_MASK -10000.0f

typedef __attribute__((ext_vector_type(8))) short bf16x8;
typedef __attribute__((ext_vector_type(4))) short s16x4;
typedef __attribute__((ext_vector_type(4))) float f32x4;
typedef __attribute__((ext_vector_type(16))) float f32x16;

__device__ __forceinline__ float bf2f(unsigned short u) {
  unsigned v = ((unsigned)u) << 16; float f; __builtin_memcpy(&f, &v, 4); return f;
}
__device__ __forceinline__ unsigned short f2bf(float f) {
  unsigned u; __builtin_memcpy(&u, &f, 4);
  unsigned r = (u + 0x7fffu + ((u >> 16) & 1u)) >> 16;
  return (unsigned short)r;
}
__device__ __forceinline__ s16x4 f2bf4(float4 v) {
  s16x4 r;
  r[0] = (short)f2bf(v.x); r[1] = (short)f2bf(v.y);
  r[2] = (short)f2bf(v.z); r[3] = (short)f2bf(v.w);
  return r;
}
__device__ __forceinline__ f32x4 mfma16(bf16x8 a, bf16x8 b, f32x4 c) {
  return __builtin_amdgcn_mfma_f32_16x16x32_bf16(a, b, c, 0, 0, 0);
}
__device__ __forceinline__ f32x16 mfma32(bf16x8 a, bf16x8 b, f32x16 c) {
  return __builtin_amdgcn_mfma_f32_32x32x16_bf16(a, b, c, 0, 0, 0);
}
__device__ __forceinline__ float block_sum256(float v, float* tmp4) {
  #pragma unroll
  for (int o = 32; o > 0; o >>= 1) v += __shfl_down(v, o);
  int wid = threadIdx.x >> 6, lane = threadIdx.x & 63;
  if (lane == 0) tmp4[wid] = v;
  __syncthreads();
  float r = tmp4[0] + tmp4[1] + tmp4[2] + tmp4[3];
  __syncthreads();
  return r;
}

// ---------------- weight prep: fp32 W[k][n] -> bf16 fragment-order swizzle ----------------
__global__ __launch_bounds__(256) void wprep_kernel(
    const float* __restrict__ Wq, const float* __restrict__ Wk,
    const float* __restrict__ Wv, const float* __restrict__ Wo,
    const float* __restrict__ Wi, const float* __restrict__ Wf,
    unsigned short* wqt, unsigned short* wkt, unsigned short* wvt,
    unsigned short* wot, unsigned short* wit, unsigned short* wft) {
  int type = blockIdx.y, ll = blockIdx.z, t = threadIdx.x;
  const float* src; unsigned short* dst; int Kd, Nd, m32;
  switch (type) {
    case 0: src = Wq + (size_t)ll * 65536;  dst = wqt + (size_t)ll * 65536;  Kd = 256;  Nd = 256;  m32 = 0; break;
    case 1: src = Wk + (size_t)ll * 65536;  dst = wkt + (size_t)ll * 65536;  Kd = 256;  Nd = 256;  m32 = 0; break;
    case 2: src = Wv + (size_t)ll * 65536;  dst = wvt + (size_t)ll * 65536;  Kd = 256;  Nd = 256;  m32 = 0; break;
    case 3: src = Wo + (size_t)ll * 65536;  dst = wot + (size_t)ll * 65536;  Kd = 256;  Nd = 256;  m32 = 0; break;
    case 4: src = Wi + (size_t)ll * 262144; dst = wit + (size_t)ll * 262144; Kd = 256;  Nd = 1024; m32 = 1; break;
    default: src = Wf + (size_t)ll * 262144; dst = wft + (size_t)ll * 262144; Kd = 1024; Nd = 256; m32 = 1; break;
  }
  int frag = blockIdx.x * 4 + (t >> 6);
  int l = t & 63;
  int nkc = m32 ? (Kd >> 4) : (Kd >> 5);
  int nfrag = (m32 ? (Nd >> 5) : (Nd >> 4)) * nkc;
  if (frag >= nfrag) return;
  int n, k0;
  if (m32) { n = (frag / nkc) * 32 + (l & 31); k0 = (frag % nkc) * 16 + (l >> 5) * 8; }
  else     { n = (frag / nkc) * 16 + (l & 15); k0 = (frag % nkc) * 32 + (l >> 4) * 8; }
  unsigned short vv[8];
  #pragma unroll
  for (int j = 0; j < 8; ++j) vv[j] = f2bf(src[(size_t)(k0 + j) * Nd + n]);
  unsigned short* o = dst + (size_t)frag * 512 + l * 8;
  #pragma unroll
  for (int j = 0; j < 8; ++j) o[j] = vv[j];
}

// ---------------- sparse prop + W_d + LN; grid (64, 2); lean LDS (34 KB) ----------------
__global__ __launch_bounds__(256) void prop_ln_kernel(
    const float* __restrict__ emb_q, const float* __restrict__ emb_k,
    const float* snq,
    const float* __restrict__ uop, const float* __restrict__ iop,
    const float* __restrict__ Wd1, const float* __restrict__ bd1,
    const float* __restrict__ g1v, const float* __restrict__ b1v,
    const float* __restrict__ Wd2, const float* __restrict__ bd2,
    const float* __restrict__ g2v, const float* __restrict__ b2v,
    float* __restrict__ out1, float* __restrict__ out2) {
  int sel = blockIdx.y;
  const float* emb = sel ? emb_k : emb_q;
  const float* op  = sel ? iop : uop;
  const float* Wd  = sel ? Wd2 : Wd1;
  const float* bd  = sel ? bd2 : bd1;
  const float* g   = sel ? g2v : g1v;
  const float* bvec= sel ? b2v : b1v;
  float* outp      = sel ? out2 : out1;
  int row = sel;
  __shared__ float s1[16 * E];
  __shared__ float s2[16 * E];
  __shared__ float wv[64];
  __shared__ int gi[64];
  __shared__ float t2row[E];
  __shared__ float tmp4[4];
  int b = blockIdx.x, e = threadIdx.x;
  if (e < 64) {
    wv[e] = op[(b * 64 + e) * 2 + 1];
    gi[e] = (int)op[(b * 64 + e) * 2 + 0];
  }
  for (int gg = 0; gg < 16; ++gg) { s1[gg * E + e] = 0.f; s2[gg * E + e] = 0.f; }
  __syncthreads();
  float t0r = 0.f;
  for (int n = 0; n < 64; ++n) {
    float t0 = 0.5f * emb[(size_t)(b * 64 + n) * E + e];
    if (snq) t0 += snq[((size_t)(b * 64 + n) * 2 + sel) * E + e];
    if (n == row) t0r = t0;
    s1[gi[n] * E + e] += wv[n] * t0;   // column-private: no races
  }
  for (int n = 0; n < 64; ++n) {
    float t0 = 0.5f * emb[(size_t)(b * 64 + n) * E + e];
    if (snq) t0 += snq[((size_t)(b * 64 + n) * 2 + sel) * E + e];
    float t1 = wv[n] * s1[gi[n] * E + e] + 0.1f * t0;
    s2[gi[n] * E + e] += wv[n] * t1;
  }
  float t2 = wv[row] * s2[gi[row] * E + e] + 0.1f * t0r;
  t2row[e] = t2;
  __syncthreads();
  float y = bd[e];
  for (int k = 0; k < E; ++k) y = fmaf(t2row[k], Wd[k * E + e], y);
  float ssum = block_sum256(y, tmp4);
  float qsum = block_sum256(y * y, tmp4);
  float m = ssum * (1.f / E);
  float var = qsum * (1.f / E) - m * m;
  outp[b * E + e] = (y - m) * rsqrtf(var + 1e-12f) * g[e] + bvec[e];
}

// ---------------- fused per-seq: K+Q proj, MFMA scores, softmax, V proj, PV ----------------
__global__ __launch_bounds__(256, 4) void seq_attn_mfma(
    const float* __restrict__ hidden,
    const unsigned short* __restrict__ wqt, const float* __restrict__ bq,
    const unsigned short* __restrict__ wkt, const float* __restrict__ bk,
    const unsigned short* __restrict__ wvt, const float* __restrict__ bv,
    const float* __restrict__ mask, unsigned short* __restrict__ ctx_all,
    unsigned short* __restrict__ Kf, unsigned short* __restrict__ Vf) {
  __shared__ __align__(16) unsigned short aT[32][264];
  __shared__ __align__(16) unsigned short kvb[32][272];
  __shared__ __align__(16) unsigned short qs16[2][264];
  __shared__ float pr[4][2][36];
  int a = blockIdx.x, t = threadIdx.x;
  int w = t >> 6, l = t & 63;
  int lm = l & 15, lkq = l >> 4, lk = lkq << 3;
  size_t hb = (size_t)a * (SEQ * E);
  #pragma unroll
  for (int i = 0; i < 8; ++i) {
    int p = i * 256 + t; int row = p >> 6, c4 = (p & 63) << 2;
    float4 v = *(const float4*)&hidden[hb + row * E + c4];
    *(s16x4*)&aT[row][c4] = f2bf4(v);
  }
  __syncthreads();
  bool isn0 = ((a & 63) == 0);
  int nb = a >> 6;
  f32x4 zz = {0.f, 0.f, 0.f, 0.f};
  #pragma unroll
  for (int nt = 0; nt < 4; ++nt) {
    int ncol = w * 64 + nt * 16 + lm;
    const unsigned short* bkrow = wkt + ((size_t)(w * 4 + nt) * 8) * 512 + l * 8;
    const unsigned short* bqrow = wqt + ((size_t)(w * 4 + nt) * 8) * 512 + l * 8;
    bf16x8 bk8[8], bq8[8];
    #pragma unroll
    for (int kc = 0; kc < 8; ++kc) bk8[kc] = *(const bf16x8*)(bkrow + kc * 512);
    #pragma unroll
    for (int kc = 0; kc < 8; ++kc) bq8[kc] = *(const bf16x8*)(bqrow + kc * 512);
    f32x4 ak0 = zz, ak1 = zz, aq = zz;
    #pragma unroll
    for (int kc = 0; kc < 8; ++kc) {
      bf16x8 a0 = *(const bf16x8*)&aT[lm][kc * 32 + lk];
      bf16x8 a1 = *(const bf16x8*)&aT[16 + lm][kc * 32 + lk];
      ak0 = mfma16(a0, bk8[kc], ak0);
      ak1 = mfma16(a1, bk8[kc], ak1);
      aq  = mfma16(a0, bq8[kc], aq);
    }
    float bb = bk[ncol];
    #pragma unroll
    for (int r = 0; r < 4; ++r) {
      int rw = (lkq << 2) + r;
      float v0 = ak0[r] + bb, v1 = ak1[r] + bb;
      kvb[rw][ncol] = f2bf(v0);
      kvb[16 + rw][ncol] = f2bf(v1);
      if (isn0) {
        Kf[((size_t)nb * 32 + rw) * 256 + ncol] = f2bf(v0);
        Kf[((size_t)nb * 32 + 16 + rw) * 256 + ncol] = f2bf(v1);
      }
    }
    if (lkq == 0) {
      float bqv = bq[ncol];
      qs16[0][ncol] = f2bf(aq[0] + bqv);
      qs16[1][ncol] = f2bf(aq[1] + bqv);
    }
  }
  __syncthreads();
  {
    f32x4 sc0 = zz, sc1 = zz;
    #pragma unroll
    for (int kc2 = 0; kc2 < 2; ++kc2) {
      bf16x8 aq = *(const bf16x8*)&qs16[lm & 1][w * 64 + kc2 * 32 + lk];
      bf16x8 b0 = *(const bf16x8*)&kvb[lm][w * 64 + kc2 * 32 + lk];
      bf16x8 b1 = *(const bf16x8*)&kvb[16 + lm][w * 64 + kc2 * 32 + lk];
      sc0 = mfma16(aq, b0, sc0);
      sc1 = mfma16(aq, b1, sc1);
    }
    float mv0 = (lm < 4) ? NEG_MASK : mask[(size_t)a * SEQ + lm];
    float mv1 = mask[(size_t)a * SEQ + 16 + lm];
    #pragma unroll
    for (int r = 0; r < 2; ++r) {
      float s0 = sc0[r] * 0.125f + mv0;
      float s1 = sc1[r] * 0.125f + mv1;
      float mx = fmaxf(s0, s1);
      mx = fmaxf(mx, __shfl_xor(mx, 1));
      mx = fmaxf(mx, __shfl_xor(mx, 2));
      mx = fmaxf(mx, __shfl_xor(mx, 4));
      mx = fmaxf(mx, __shfl_xor(mx, 8));
      float e0 = expf(s0 - mx), e1 = expf(s1 - mx);
      float se = e0 + e1;
      se += __shfl_xor(se, 1); se += __shfl_xor(se, 2);
      se += __shfl_xor(se, 4); se += __shfl_xor(se, 8);
      float inv = 1.f / se;
      if (lkq == 0) {
        pr[w][r][lm] = e0 * inv;
        pr[w][r][16 + lm] = e1 * inv;
      }
    }
  }
  __syncthreads();
  #pragma unroll
  for (int nt = 0; nt < 4; ++nt) {
    int ncol = w * 64 + nt * 16 + lm;
    const unsigned short* bvrow = wvt + ((size_t)(w * 4 + nt) * 8) * 512 + l * 8;
    bf16x8 bv8[8];
    #pragma unroll
    for (int kc = 0; kc < 8; ++kc) bv8[kc] = *(const bf16x8*)(bvrow + kc * 512);
    f32x4 av0 = zz, av1 = zz;
    #pragma unroll
    for (int kc = 0; kc < 8; ++kc) {
      bf16x8 a0 = *(const bf16x8*)&aT[lm][kc * 32 + lk];
      bf16x8 a1 = *(const bf16x8*)&aT[16 + lm][kc * 32 + lk];
      av0 = mfma16(a0, bv8[kc], av0);
      av1 = mfma16(a1, bv8[kc], av1);
    }
    float bb = bv[ncol];
    #pragma unroll
    for (int r = 0; r < 4; ++r) {
      int rw = (lkq << 2) + r;
      float v0 = av0[r] + bb, v1 = av1[r] + bb;
      kvb[rw][ncol] = f2bf(v0);
      kvb[16 + rw][ncol] = f2bf(v1);
      if (isn0) {
        Vf[((size_t)nb * 32 + rw) * 256 + ncol] = f2bf(v0);
        Vf[((size_t)nb * 32 + 16 + rw) * 256 + ncol] = f2bf(v1);
      }
    }
  }
  __syncthreads();
  {
    float o0 = 0.f, o1 = 0.f;
    #pragma unroll
    for (int tt = 0; tt < 32; ++tt) {
      float vv = bf2f(kvb[tt][t]);
      o0 = fmaf(pr[w][0][tt], vv, o0);
      o1 = fmaf(pr[w][1][tt], vv, o1);
    }
    ctx_all[((size_t)a * 2 + 0) * E + t] = f2bf(o0);
    ctx_all[((size_t)a * 2 + 1) * E + t] = f2bf(o1);
  }
}

// ---------------- Q projection for n0 rows (gathered A), swizzled B ----------------
__global__ __launch_bounds__(256) void gemm_bias_kernel(
    const float* __restrict__ Af, const unsigned short* __restrict__ Bt,
    const float* __restrict__ bias, unsigned short* __restrict__ outb) {
  __shared__ __align__(16) unsigned short aT[32][264];
  int t = threadIdx.x, w = t >> 6, l = t & 63;
  int lm = l & 15, lkq = l >> 4, lk = lkq << 3;
  int row0 = blockIdx.x * 32;
  #pragma unroll
  for (int i = 0; i < 8; ++i) {
    int p = i * 256 + t; int row = p >> 6, c4 = (p & 63) << 2;
    int gr = row0 + row;
    int src = ((gr >> 5) << 11) + (gr & 31);
    float4 v = *(const float4*)&Af[(size_t)src * E + c4];
    *(s16x4*)&aT[row][c4] = f2bf4(v);
  }
  __syncthreads();
  f32x4 zz = {0.f, 0.f, 0.f, 0.f};
  #pragma unroll
  for (int nt = 0; nt < 4; ++nt) {
    int ncol = w * 64 + nt * 16 + lm;
    const unsigned short* brow = Bt + ((size_t)(w * 4 + nt) * 8) * 512 + l * 8;
    bf16x8 b8[8];
    #pragma unroll
    for (int kc = 0; kc < 8; ++kc) b8[kc] = *(const bf16x8*)(brow + kc * 512);
    f32x4 c0 = zz, c1 = zz;
    #pragma unroll
    for (int kc = 0; kc < 8; ++kc) {
      bf16x8 a0 = *(const bf16x8*)&aT[lm][kc * 32 + lk];
      bf16x8 a1 = *(const bf16x8*)&aT[16 + lm][kc * 32 + lk];
      c0 = mfma16(a0, b8[kc], c0);
      c1 = mfma16(a1, b8[kc], c1);
    }
    float bb = bias[ncol];
    #pragma unroll
    for (int r = 0; r < 4; ++r) {
      int rw = (lkq << 2) + r;
      outb[(size_t)(row0 + rw) * E + ncol] = f2bf(c0[r] + bb);
      outb[(size_t)(row0 + 16 + rw) * E + ncol] = f2bf(c1[r] + bb);
    }
  }
}

// ---------------- iter-1 QKV: grid (seq, matrix) ----------------
__global__ __launch_bounds__(256) void qkv1_kernel(
    const unsigned short* __restrict__ Ab,
    const unsigned short* __restrict__ wq, const float* __restrict__ bqv,
    const unsigned short* __restrict__ wk, const float* __restrict__ bkv,
    const unsigned short* __restrict__ wv, const float* __restrict__ bvv,
    unsigned short* q2, unsigned short* k2, unsigned short* v2) {
  __shared__ __align__(16) unsigned short aT[32][264];
  int t = threadIdx.x, w = t >> 6, l = t & 63;
  int lm = l & 15, lkq = l >> 4, lk = lkq << 3;
  int row0 = blockIdx.x * 32;
  int m = blockIdx.y;
  const unsigned short* Wt = (m == 0) ? wq : (m == 1) ? wk : wv;
  const float* bb = (m == 0) ? bqv : (m == 1) ? bkv : bvv;
  unsigned short* outb = (m == 0) ? q2 : (m == 1) ? k2 : v2;
  #pragma unroll
  for (int i = 0; i < 4; ++i) {
    int p = i * 256 + t; int row = p >> 5, c8 = (p & 31) << 3;
    *(s16x4*)&aT[row][c8] = *(const s16x4*)&Ab[(size_t)(row0 + row) * E + c8];
    *(s16x4*)&aT[row][c8 + 4] = *(const s16x4*)&Ab[(size_t)(row0 + row) * E + c8 + 4];
  }
  __syncthreads();
  f32x4 zz = {0.f, 0.f, 0.f, 0.f};
  #pragma unroll
  for (int nt = 0; nt < 4; ++nt) {
    int ncol = w * 64 + nt * 16 + lm;
    const unsigned short* brow = Wt + ((size_t)(w * 4 + nt) * 8) * 512 + l * 8;
    bf16x8 b8[8];
    #pragma unroll
    for (int kc = 0; kc < 8; ++kc) b8[kc] = *(const bf16x8*)(brow + kc * 512);
    f32x4 c0 = zz, c1 = zz;
    #pragma unroll
    for (int kc = 0; kc < 8; ++kc) {
      bf16x8 a0 = *(const bf16x8*)&aT[lm][kc * 32 + lk];
      bf16x8 a1 = *(const bf16x8*)&aT[16 + lm][kc * 32 + lk];
      c0 = mfma16(a0, b8[kc], c0);
      c1 = mfma16(a1, b8[kc], c1);
    }
    float bv2 = bb[ncol];
    #pragma unroll
    for (int r = 0; r < 4; ++r) {
      int rw = (lkq << 2) + r;
      outb[(size_t)(row0 + rw) * E + ncol] = f2bf(c0[r] + bv2);
      outb[(size_t)(row0 + 16 + rw) * E + ncol] = f2bf(c1[r] + bv2);
    }
  }
}

// ---------------- full attention (bf16 in/out), compact 64-seq buffers ----------------
__global__ __launch_bounds__(256) void attnf_kernel(
    const unsigned short* __restrict__ Q, const unsigned short* __restrict__ K,
    const unsigned short* __restrict__ V, unsigned short* __restrict__ CTX,
    const float* __restrict__ mask, int set4) {
  int b = blockIdx.x, h = blockIdx.y, t = threadIdx.x;
  __shared__ float qsh[32][65], ksh[32][65], vsh[32][65];
  __shared__ float pr[32][33];
  size_t base = (size_t)b * (SEQ * E) + h * 64;
  for (int i = 0; i < 8; ++i) {
    int p = i * 256 + t; int s = p >> 6, d = p & 63;
    qsh[s][d] = bf2f(Q[base + s * E + d]);
    ksh[s][d] = bf2f(K[base + s * E + d]);
    vsh[s][d] = bf2f(V[base + s * E + d]);
  }
  __syncthreads();
  for (int i = 0; i < 4; ++i) {
    int p = i * 256 + t; int s = p >> 5, tt = p & 31;
    float acc = 0.f;
    #pragma unroll
    for (int d = 0; d < 64; ++d) acc = fmaf(qsh[s][d], ksh[tt][d], acc);
    float mv = mask[(size_t)b * 2048 + tt];
    if (set4 && tt < 4) mv = NEG_MASK;
    pr[s][tt] = acc * 0.125f + mv;
  }
  __syncthreads();
  int rrow = t >> 3, l8 = t & 7;
  float vals[4];
  float mx = -1e30f;
  #pragma unroll
  for (int ii = 0; ii < 4; ++ii) { vals[ii] = pr[rrow][l8 + ii * 8]; mx = fmaxf(mx, vals[ii]); }
  mx = fmaxf(mx, __shfl_xor(mx, 1));
  mx = fmaxf(mx, __shfl_xor(mx, 2));
  mx = fmaxf(mx, __shfl_xor(mx, 4));
  float se = 0.f;
  #pragma unroll
  for (int ii = 0; ii < 4; ++ii) { vals[ii] = expf(vals[ii] - mx); se += vals[ii]; }
  se += __shfl_xor(se, 1); se += __shfl_xor(se, 2); se += __shfl_xor(se, 4);
  float inv = 1.f / se;
  #pragma unroll
  for (int ii = 0; ii < 4; ++ii) pr[rrow][l8 + ii * 8] = vals[ii] * inv;
  __syncthreads();
  for (int i = 0; i < 8; ++i) {
    int p = i * 256 + t; int s = p >> 6, d = p & 63;
    float acc = 0.f;
    #pragma unroll
    for (int tt = 0; tt < SEQ; ++tt) acc = fmaf(pr[s][tt], vsh[tt][d], acc);
    CTX[base + s * E + d] = f2bf(acc);
  }
}

__device__ __forceinline__ int map_res(int gr) {
  if (gr < 8192) return ((gr >> 1) << 5) + (gr & 1);
  int rr = gr - 8192;
  return ((rr >> 5) << 11) + (rr & 31);
}

// ---------------- tailA: Wo GEMM + LN1 -> a_bf (bf16) + a_f32 ----------------
__global__ __launch_bounds__(256) void tailA_mfma(
    const unsigned short* __restrict__ ctx,
    const unsigned short* __restrict__ wo, const float* __restrict__ bo,
    const float* __restrict__ Res, int resmode,
    const float* __restrict__ g1, const float* __restrict__ b1,
    unsigned short* __restrict__ a_bf, float* __restrict__ a_f32) {
  __shared__ __align__(16) unsigned short aT[32][264];
  __shared__ float sT[32][257];
  __shared__ float prs[32][4], prq[32][4];
  int t = threadIdx.x, w = t >> 6, l = t & 63;
  int row0 = blockIdx.x * 32;
  #pragma unroll
  for (int i = 0; i < 8; ++i) {
    int p = i * 256 + t; int row = p >> 6, c4 = (p & 63) << 2;
    *(s16x4*)&aT[row][c4] = *(const s16x4*)&ctx[(size_t)(row0 + row) * E + c4];
  }
  __syncthreads();
  {
    int lm = l & 15, lkq = l >> 4, lk = lkq << 3;
    f32x4 zz = {0.f, 0.f, 0.f, 0.f};
    #pragma unroll
    for (int nt = 0; nt < 4; ++nt) {
      int ncol = w * 64 + nt * 16 + lm;
      const unsigned short* brow = wo + ((size_t)(w * 4 + nt) * 8) * 512 + l * 8;
      bf16x8 b8[8];
      #pragma unroll
      for (int kc = 0; kc < 8; ++kc) b8[kc] = *(const bf16x8*)(brow + kc * 512);
      f32x4 c0 = zz, c1 = zz;
      #pragma unroll
      for (int kc = 0; kc < 8; ++kc) {
        bf16x8 a0 = *(const bf16x8*)&aT[lm][kc * 32 + lk];
        bf16x8 a1 = *(const bf16x8*)&aT[16 + lm][kc * 32 + lk];
        c0 = mfma16(a0, b8[kc], c0);
        c1 = mfma16(a1, b8[kc], c1);
      }
      float bb = bo[ncol];
      #pragma unroll
      for (int r = 0; r < 4; ++r) {
        int rw = (lkq << 2) + r;
        int rr0 = resmode ? map_res(row0 + rw) : (row0 + rw);
        int rr1 = resmode ? map_res(row0 + 16 + rw) : (row0 + 16 + rw);
        sT[rw][ncol] = c0[r] + bb + Res[(size_t)rr0 * E + ncol];
        sT[16 + rw][ncol] = c1[r] + bb + Res[(size_t)rr1 * E + ncol];
      }
    }
  }
  __syncthreads();
  {
    int wid = t >> 6, lane = t & 63;
    float vcache[32];
    for (int r = 0; r < 32; ++r) {
      float v = sT[r][t];
      vcache[r] = v;
      float s = v, q = v * v;
      #pragma unroll
      for (int o = 32; o > 0; o >>= 1) { s += __shfl_down(s, o); q += __shfl_down(q, o); }
      if (lane == 0) { prs[r][wid] = s; prq[r][wid] = q; }
    }
    __syncthreads();
    #pragma unroll
    for (int r = 0; r < 32; ++r) {
      float Sv = prs[r][0] + prs[r][1] + prs[r][2] + prs[r][3];
      float Qv = prq[r][0] + prq[r][1] + prq[r][2] + prq[r][3];
      float m = Sv * (1.f / E), var = Qv * (1.f / E) - m * m;
      float val = (vcache[r] - m) * rsqrtf(var + 1e-12f) * g1[t] + b1[t];
      a_f32[(size_t)(row0 + r) * E + t] = val;
      a_bf[(size_t)(row0 + r) * E + t] = f2bf(val);
    }
  }
}

// ---------------- ffnB: one FF-quarter GEMM1 + gelu + partial GEMM2 (512 thr); bf16 partials ----------------
__global__ __launch_bounds__(512) void ffnB_kernel(
    const unsigned short* __restrict__ a_bf,
    const unsigned short* __restrict__ wi, const float* __restrict__ bi,
    const unsigned short* __restrict__ wf,
    unsigned short* __restrict__ part, size_t pstride) {
  __shared__ __align__(16) unsigned short aT[32][264];
  __shared__ __align__(16) unsigned short fT[32][264];
  int t = threadIdx.x, w = t >> 6, l = t & 63;
  int lm = l & 31, lk = (l >> 5) << 3;
  int row0 = blockIdx.x * 32, qh = blockIdx.y;
  #pragma unroll
  for (int i = 0; i < 2; ++i) {
    int chunk = i * 512 + t; int row = chunk >> 5, c8 = (chunk & 31) << 3;
    *(s16x4*)&aT[row][c8] = *(const s16x4*)&a_bf[(size_t)(row0 + row) * E + c8];
    *(s16x4*)&aT[row][c8 + 4] = *(const s16x4*)&a_bf[(size_t)(row0 + row) * E + c8 + 4];
  }
  __syncthreads();
  f32x16 zz16 = {0};
  {
    const unsigned short* brow = wi + ((size_t)(qh * 8 + w) * 16) * 512 + l * 8;
    bf16x8 b16[16];
    #pragma unroll
    for (int kc = 0; kc < 16; ++kc) b16[kc] = *(const bf16x8*)(brow + kc * 512);
    f32x16 c = zz16;
    #pragma unroll
    for (int kc = 0; kc < 16; ++kc) {
      bf16x8 a = *(const bf16x8*)&aT[lm][kc * 16 + lk];
      c = mfma32(a, b16[kc], c);
    }
    int lcol = w * 32 + lm;
    float bib = bi[qh * 256 + lcol];
    #pragma unroll
    for (int reg = 0; reg < 16; ++reg) {
      int row = (reg & 3) + 8 * (reg >> 2) + 4 * (l >> 5);
      float x = c[reg] + bib;
      fT[row][lcol] = f2bf(0.5f * x * (1.f + erff(x * 0.70710678118654752f)));
    }
  }
  __syncthreads();
  {
    const unsigned short* brow = wf + ((size_t)(w * 64 + qh * 16)) * 512 + l * 8;
    bf16x8 b16[16];
    #pragma unroll
    for (int kc = 0; kc < 16; ++kc) b16[kc] = *(const bf16x8*)(brow + kc * 512);
    f32x16 c = zz16;
    #pragma unroll
    for (int kc = 0; kc < 16; ++kc) {
      bf16x8 a = *(const bf16x8*)&fT[lm][kc * 16 + lk];
      c = mfma32(a, b16[kc], c);
    }
    unsigned short* po = part + (size_t)qh * pstride;
    int col = w * 32 + lm;
    #pragma unroll
    for (int reg = 0; reg < 16; ++reg) {
      int row = (reg & 3) + 8 * (reg >> 2) + 4 * (l >> 5);
      po[(size_t)(row0 + row) * E + col] = f2bf(c[reg]);
    }
  }
}

// ---------------- ffnC: sum 4 bf16 partials + bias + residual + LN2 ----------------
__global__ __launch_bounds__(256) void ffnC_kernel(
    const unsigned short* __restrict__ part, size_t pstride,
    const float* __restrict__ bfv, const float* __restrict__ a_f32,
    const float* __restrict__ g2, const float* __restrict__ b2,
    float* __restrict__ out0, float* __restrict__ out1, int split) {
  __shared__ float prs[32][4], prq[32][4];
  int t = threadIdx.x;
  int row0 = blockIdx.x * 32;
  int wid = t >> 6, lane = t & 63;
  float bb = bfv[t];
  float vcache[32];
  for (int r = 0; r < 32; ++r) {
    size_t idx = (size_t)(row0 + r) * E + t;
    float v = bf2f(part[idx]) + bf2f(part[pstride + idx]) +
              bf2f(part[2 * pstride + idx]) + bf2f(part[3 * pstride + idx]) +
              bb + a_f32[idx];
    vcache[r] = v;
    float s = v, q = v * v;
    #pragma unroll
    for (int o = 32; o > 0; o >>= 1) { s += __shfl_down(s, o); q += __shfl_down(q, o); }
    if (lane == 0) { prs[r][wid] = s; prq[r][wid] = q; }
  }
  __syncthreads();
  #pragma unroll
  for (int r = 0; r < 32; ++r) {
    float Sv = prs[r][0] + prs[r][1] + prs[r][2] + prs[r][3];
    float Qv = prq[r][0] + prq[r][1] + prq[r][2] + prq[r][3];
    float m = Sv * (1.f / E), var = Qv * (1.f / E) - m * m;
    float val = (vcache[r] - m) * rsqrtf(var + 1e-12f) * g2[t] + b2[t];
    int gr = row0 + r;
    if (gr < split) out0[(size_t)gr * E + t] = val;
    else            out1[(size_t)(gr - split) * E + t] = val;
  }
}

// ---------------- fused agg (iter0) + build iter-1 input ----------------
__global__ __launch_bounds__(256) void agg_build_kernel(
    const float* __restrict__ h1n0,
    const float* __restrict__ p1, const float* __restrict__ p2,
    const float* __restrict__ Wagg, const float* __restrict__ bagg,
    const float* __restrict__ qe, const float* __restrict__ ke,
    const float* __restrict__ de, const float* __restrict__ ce,
    float* __restrict__ agg0,
    float* __restrict__ h2f, unsigned short* __restrict__ h2b) {
  __shared__ float pv[768];
  __shared__ float tmp4[4];
  int b = blockIdx.x, t = threadIdx.x;
  float x = h1n0[(size_t)b * (SEQ * E) + 4 * E + t];
  float n2 = block_sum256(x * x, tmp4);
  pv[t] = x / fmaxf(sqrtf(n2), 1e-12f);
  pv[256 + t] = p1[b * E + t];
  pv[512 + t] = p2[b * E + t];
  __syncthreads();
  float y = bagg[t];
  for (int u = 0; u < 768; ++u) y = fmaf(pv[u], Wagg[u * E + t], y);
  y = fmaxf(y, 0.f);
  float n3 = block_sum256(y * y, tmp4);
  float aggv = y / fmaxf(sqrtf(n3), 1e-12f);
  agg0[b * E + t] = aggv;
  size_t eb = (size_t)(b * 64) * E + t;
  size_t ob = (size_t)b * (SEQ * E);
  float v;
  v = qe[eb];  h2f[ob + 0 * E + t] = v; h2b[ob + 0 * E + t] = f2bf(v);
  v = ke[eb];  h2f[ob + 1 * E + t] = v; h2b[ob + 1 * E + t] = f2bf(v);
  v = de[eb];  h2f[ob + 2 * E + t] = v; h2b[ob + 2 * E + t] = f2bf(v);
  v = ce[eb];  h2f[ob + 3 * E + t] = v; h2b[ob + 3 * E + t] = f2bf(v);
  h2f[ob + 4 * E + t] = aggv; h2b[ob + 4 * E + t] = f2bf(aggv);
  for (int s = 5; s < SEQ; ++s) {
    v = h1n0[ob + s * E + t];
    h2f[ob + s * E + t] = v; h2b[ob + s * E + t] = f2bf(v);
  }
}

// ---------------- fused agg (iter1) + final output ----------------
__global__ __launch_bounds__(256) void agg_out_kernel(
    const float* __restrict__ h2,
    const float* __restrict__ p1, const float* __restrict__ p2,
    const float* __restrict__ Wagg, const float* __restrict__ bagg,
    const float* __restrict__ h1n0, const float* __restrict__ agg0,
    float* __restrict__ outp) {
  __shared__ float pv[768];
  __shared__ float tmp4[4];
  int b = blockIdx.x, t = threadIdx.x;
  float x = h2[(size_t)b * (SEQ * E) + 4 * E + t];
  float n2 = block_sum256(x * x, tmp4);
  pv[t] = x / fmaxf(sqrtf(n2), 1e-12f);
  pv[256 + t] = p1[b * E + t];
  pv[512 + t] = p2[b * E + t];
  __syncthreads();
  float y = bagg[t];
  for (int u = 0; u < 768; ++u) y = fmaf(pv[u], Wagg[u * E + t], y);
  y = fmaxf(y, 0.f);
  float n3 = block_sum256(y * y, tmp4);
  float agg1v = y / fmaxf(sqrtf(n3), 1e-12f);
  size_t ob = (size_t)b * (SEQ * E);
  float s1v = agg0[b * E + t];
  float s2v = agg1v;
  for (int s = 5; s < SEQ; ++s) { s1v += h1n0[ob + s * E + t]; s2v += h2[ob + s * E + t]; }
  outp[b * E + t] = 0.5f * (s1v + s2v) * (1.f / 28.f);
}

extern "C" void kernel_launch(void* const* d_in, const int* in_sizes, int n_in,
                              void* d_out, int out_size, void* d_ws, size_t ws_size,
                              hipStream_t stream) {
  (void)in_sizes; (void)n_in; (void)out_size;
  const float* hidden = (const float*)d_in[1];
  const float* amask  = (const float*)d_in[2];
  const float* qemb   = (const float*)d_in[3];
  const float* kemb   = (const float*)d_in[4];
  const float* demb   = (const float*)d_in[5];
  const float* cemb   = (const float*)d_in[6];
  const float* uop    = (const float*)d_in[7];
  const float* iop    = (const float*)d_in[8];
  const float* Wq = (const float*)d_in[9];  const float* bq = (const float*)d_in[10];
  const float* Wk = (const float*)d_in[11]; const float* bk = (const float*)d_in[12];
  const float* Wv = (const float*)d_in[13]; const float* bv = (const float*)d_in[14];
  const float* Wo = (const float*)d_in[15]; const float* bo = (const float*)d_in[16];
  const float* g1 = (const float*)d_in[17]; const float* b1 = (const float*)d_in[18];
  const float* Wi = (const float*)d_in[19]; const float* bi = (const float*)d_in[20];
  const float* Wf = (const float*)d_in[21]; const float* bf = (const float*)d_in[22];
  const float* g2 = (const float*)d_in[23]; const float* b2 = (const float*)d_in[24];
  const float* Wagg = (const float*)d_in[25]; const float* bagg = (const float*)d_in[26];
  const float* Wd1 = (const float*)d_in[27]; const float* bd1 = (const float*)d_in[28];
  const float* l1g = (const float*)d_in[29]; const float* l1b = (const float*)d_in[30];
  const float* Wd2 = (const float*)d_in[31]; const float* bd2 = (const float*)d_in[32];
  const float* l2g = (const float*)d_in[33]; const float* l2b = (const float*)d_in[34];

  // ---- workspace carve ----
  char* cur = (char*)d_ws;
  auto alloc_us = [&](size_t n) { unsigned short* p = (unsigned short*)cur; cur += ((n * 2 + 255) & ~(size_t)255); return p; };
  auto alloc_f  = [&](size_t n) { float* p = (float*)cur; cur += ((n * 4 + 255) & ~(size_t)255); return p; };
  unsigned short* wqt = alloc_us(131072);
  unsigned short* wkt = alloc_us(131072);
  unsigned short* wvt = alloc_us(131072);
  unsigned short* wot = alloc_us(131072);
  unsigned short* wit = alloc_us(524288);
  unsigned short* wft = alloc_us(524288);
  unsigned short* ctx_all = alloc_us((size_t)10240 * 256);
  unsigned short* qn0 = alloc_us((size_t)2048 * 256);
  unsigned short* Kf  = alloc_us((size_t)2048 * 256);
  unsigned short* Vf  = alloc_us((size_t)2048 * 256);
  unsigned short* h2inb = alloc_us((size_t)2048 * 256);
  unsigned short* a_bf = alloc_us((size_t)10240 * 256);
  unsigned short* q2b = alloc_us((size_t)2048 * 256);
  unsigned short* k2b = alloc_us((size_t)2048 * 256);
  unsigned short* v2b = alloc_us((size_t)2048 * 256);
  unsigned short* ctx1 = alloc_us((size_t)2048 * 256);
  unsigned short* part = alloc_us((size_t)4 * 10240 * 256);
  float* a_f32 = alloc_f((size_t)10240 * 256);
  float* h101  = alloc_f((size_t)4096 * 2 * 256);
  float* h1n0  = alloc_f((size_t)2048 * 256);
  float* h2inf = alloc_f((size_t)2048 * 256);
  float* h2    = alloc_f((size_t)2048 * 256);
  float* p1_0  = alloc_f(64 * 256);
  float* p2_0  = alloc_f(64 * 256);
  float* p1_1  = alloc_f(64 * 256);
  float* p2_1  = alloc_f(64 * 256);
  float* agg0  = alloc_f(64 * 256);
  if ((size_t)(cur - (char*)d_ws) > ws_size) return;
  const size_t PSTRIDE = (size_t)10240 * 256;

  // ---- weight prep (fragment-order swizzle) ----
  wprep_kernel<<<dim3(128, 6, 2), 256, 0, stream>>>(Wq, Wk, Wv, Wo, Wi, Wf,
                                                    wqt, wkt, wvt, wot, wit, wft);

  // ================= iteration 0 =================
  prop_ln_kernel<<<dim3(64, 2), 256, 0, stream>>>(qemb, kemb, nullptr, uop, iop,
                                                  Wd1, bd1, l1g, l1b, Wd2, bd2, l2g, l2b,
                                                  p1_0, p2_0);
  seq_attn_mfma<<<4096, 256, 0, stream>>>(hidden, wqt, bq, wkt, bk, wvt, bv,
                                          amask, ctx_all, Kf, Vf);
  gemm_bias_kernel<<<64, 256, 0, stream>>>(hidden, wqt, bq, qn0);
  attnf_kernel<<<dim3(64, 4), 256, 0, stream>>>(qn0, Kf, Vf, ctx_all + (size_t)8192 * 256,
                                                amask, 1);
  tailA_mfma<<<320, 256, 0, stream>>>(ctx_all, wot, bo, hidden, 1, g1, b1, a_bf, a_f32);
  ffnB_kernel<<<dim3(320, 4), 512, 0, stream>>>(a_bf, wit, bi, wft, part, PSTRIDE);
  ffnC_kernel<<<320, 256, 0, stream>>>(part, PSTRIDE, bf, a_f32, g2, b2,
                                       h101, h1n0, 8192);
  agg_build_kernel<<<64, 256, 0, stream>>>(h1n0, p1_0, p2_0, Wagg, bagg,
                                           qemb, kemb, demb, cemb, agg0, h2inf, h2inb);

  // ================= iteration 1 =================
  prop_ln_kernel<<<dim3(64, 2), 256, 0, stream>>>(qemb, kemb, h101, uop, iop,
                                                  Wd1, bd1, l1g, l1b, Wd2, bd2, l2g, l2b,
                                                  p1_1, p2_1);
  qkv1_kernel<<<dim3(64, 3), 256, 0, stream>>>(h2inb,
                                               wqt + 65536, bq + E,
                                               wkt + 65536, bk + E,
                                               wvt + 65536, bv + E,
                                               q2b, k2b, v2b);
  attnf_kernel<<<dim3(64, 4), 256, 0, stream>>>(q2b, k2b, v2b, ctx1, amask, 0);
  tailA_mfma<<<64, 256, 0, stream>>>(ctx1, wot + 65536, bo + E, h2inf, 0,
                                     g1 + E, b1 + E, a_bf, a_f32);
  ffnB_kernel<<<dim3(64, 4), 512, 0, stream>>>(a_bf, wit + 262144, bi + FF,
                                               wft + 262144, part, PSTRIDE);
  ffnC_kernel<<<64, 256, 0, stream>>>(part, PSTRIDE, bf + E, a_f32,
                                      g2 + E, b2 + E, h2, h2, 1 << 30);
  agg_out_kernel<<<64, 256, 0, stream>>>(h2, p1_1, p2_1,
                                         Wagg + (size_t)768 * E, bagg + E,
                                         h1n0, agg0, (float*)d_out);
}

// Round 14
// 376.235 us; speedup vs baseline: 1.0602x; 1.0189x over previous
//
#include <hip/hip_runtime.h>
#include <math.h>

#define E 256
#define SEQ 32
#define FF 1024
#define NEG_MASK -10000.0f

typedef __attribute__((ext_vector_type(8))) short bf16x8;
typedef __attribute__((ext_vector_type(4))) short s16x4;
typedef __attribute__((ext_vector_type(4))) float f32x4;
typedef __attribute__((ext_vector_type(16))) float f32x16;

__device__ __forceinline__ float bf2f(unsigned short u) {
  unsigned v = ((unsigned)u) << 16; float f; __builtin_memcpy(&f, &v, 4); return f;
}
__device__ __forceinline__ unsigned short f2bf(float f) {
  unsigned u; __builtin_memcpy(&u, &f, 4);
  unsigned r = (u + 0x7fffu + ((u >> 16) & 1u)) >> 16;
  return (unsigned short)r;
}
__device__ __forceinline__ s16x4 f2bf4(float4 v) {
  s16x4 r;
  r[0] = (short)f2bf(v.x); r[1] = (short)f2bf(v.y);
  r[2] = (short)f2bf(v.z); r[3] = (short)f2bf(v.w);
  return r;
}
__device__ __forceinline__ f32x4 mfma16(bf16x8 a, bf16x8 b, f32x4 c) {
  return __builtin_amdgcn_mfma_f32_16x16x32_bf16(a, b, c, 0, 0, 0);
}
__device__ __forceinline__ f32x16 mfma32(bf16x8 a, bf16x8 b, f32x16 c) {
  return __builtin_amdgcn_mfma_f32_32x32x16_bf16(a, b, c, 0, 0, 0);
}
__device__ __forceinline__ float block_sum256(float v, float* tmp4) {
  #pragma unroll
  for (int o = 32; o > 0; o >>= 1) v += __shfl_down(v, o);
  int wid = threadIdx.x >> 6, lane = threadIdx.x & 63;
  if (lane == 0) tmp4[wid] = v;
  __syncthreads();
  float r = tmp4[0] + tmp4[1] + tmp4[2] + tmp4[3];
  __syncthreads();
  return r;
}

// ---------------- weight prep: fp32 W[k][n] -> bf16 fragment-order swizzle ----------------
__global__ __launch_bounds__(256) void wprep_kernel(
    const float* __restrict__ Wq, const float* __restrict__ Wk,
    const float* __restrict__ Wv, const float* __restrict__ Wo,
    const float* __restrict__ Wi, const float* __restrict__ Wf,
    unsigned short* wqt, unsigned short* wkt, unsigned short* wvt,
    unsigned short* wot, unsigned short* wit, unsigned short* wft) {
  int type = blockIdx.y, ll = blockIdx.z, t = threadIdx.x;
  const float* src; unsigned short* dst; int Kd, Nd, m32;
  switch (type) {
    case 0: src = Wq + (size_t)ll * 65536;  dst = wqt + (size_t)ll * 65536;  Kd = 256;  Nd = 256;  m32 = 0; break;
    case 1: src = Wk + (size_t)ll * 65536;  dst = wkt + (size_t)ll * 65536;  Kd = 256;  Nd = 256;  m32 = 0; break;
    case 2: src = Wv + (size_t)ll * 65536;  dst = wvt + (size_t)ll * 65536;  Kd = 256;  Nd = 256;  m32 = 0; break;
    case 3: src = Wo + (size_t)ll * 65536;  dst = wot + (size_t)ll * 65536;  Kd = 256;  Nd = 256;  m32 = 0; break;
    case 4: src = Wi + (size_t)ll * 262144; dst = wit + (size_t)ll * 262144; Kd = 256;  Nd = 1024; m32 = 1; break;
    default: src = Wf + (size_t)ll * 262144; dst = wft + (size_t)ll * 262144; Kd = 1024; Nd = 256; m32 = 1; break;
  }
  int frag = blockIdx.x * 4 + (t >> 6);
  int l = t & 63;
  int nkc = m32 ? (Kd >> 4) : (Kd >> 5);
  int nfrag = (m32 ? (Nd >> 5) : (Nd >> 4)) * nkc;
  if (frag >= nfrag) return;
  int n, k0;
  if (m32) { n = (frag / nkc) * 32 + (l & 31); k0 = (frag % nkc) * 16 + (l >> 5) * 8; }
  else     { n = (frag / nkc) * 16 + (l & 15); k0 = (frag % nkc) * 32 + (l >> 4) * 8; }
  unsigned short vv[8];
  #pragma unroll
  for (int j = 0; j < 8; ++j) vv[j] = f2bf(src[(size_t)(k0 + j) * Nd + n]);
  unsigned short* o = dst + (size_t)frag * 512 + l * 8;
  #pragma unroll
  for (int j = 0; j < 8; ++j) o[j] = vv[j];
}

// ---------------- sparse prop + W_d + LN; grid (64, 2); lean LDS (34 KB) ----------------
__global__ __launch_bounds__(256) void prop_ln_kernel(
    const float* __restrict__ emb_q, const float* __restrict__ emb_k,
    const float* snq,
    const float* __restrict__ uop, const float* __restrict__ iop,
    const float* __restrict__ Wd1, const float* __restrict__ bd1,
    const float* __restrict__ g1v, const float* __restrict__ b1v,
    const float* __restrict__ Wd2, const float* __restrict__ bd2,
    const float* __restrict__ g2v, const float* __restrict__ b2v,
    float* __restrict__ out1, float* __restrict__ out2) {
  int sel = blockIdx.y;
  const float* emb = sel ? emb_k : emb_q;
  const float* op  = sel ? iop : uop;
  const float* Wd  = sel ? Wd2 : Wd1;
  const float* bd  = sel ? bd2 : bd1;
  const float* g   = sel ? g2v : g1v;
  const float* bvec= sel ? b2v : b1v;
  float* outp      = sel ? out2 : out1;
  int row = sel;
  __shared__ float s1[16 * E];
  __shared__ float s2[16 * E];
  __shared__ float wv[64];
  __shared__ int gi[64];
  __shared__ float t2row[E];
  __shared__ float tmp4[4];
  int b = blockIdx.x, e = threadIdx.x;
  if (e < 64) {
    wv[e] = op[(b * 64 + e) * 2 + 1];
    gi[e] = (int)op[(b * 64 + e) * 2 + 0];
  }
  for (int gg = 0; gg < 16; ++gg) { s1[gg * E + e] = 0.f; s2[gg * E + e] = 0.f; }
  __syncthreads();
  float t0r = 0.f;
  for (int n = 0; n < 64; ++n) {
    float t0 = 0.5f * emb[(size_t)(b * 64 + n) * E + e];
    if (snq) t0 += snq[((size_t)(b * 64 + n) * 2 + sel) * E + e];
    if (n == row) t0r = t0;
    s1[gi[n] * E + e] += wv[n] * t0;   // column-private: no races
  }
  for (int n = 0; n < 64; ++n) {
    float t0 = 0.5f * emb[(size_t)(b * 64 + n) * E + e];
    if (snq) t0 += snq[((size_t)(b * 64 + n) * 2 + sel) * E + e];
    float t1 = wv[n] * s1[gi[n] * E + e] + 0.1f * t0;
    s2[gi[n] * E + e] += wv[n] * t1;
  }
  float t2 = wv[row] * s2[gi[row] * E + e] + 0.1f * t0r;
  t2row[e] = t2;
  __syncthreads();
  float y = bd[e];
  for (int k = 0; k < E; ++k) y = fmaf(t2row[k], Wd[k * E + e], y);
  float ssum = block_sum256(y, tmp4);
  float qsum = block_sum256(y * y, tmp4);
  float m = ssum * (1.f / E);
  float var = qsum * (1.f / E) - m * m;
  outp[b * E + e] = (y - m) * rsqrtf(var + 1e-12f) * g[e] + bvec[e];
}

// ---------------- fused per-seq, 512 threads (8 waves): K+Q proj, MFMA scores, softmax, V proj, PV ----------------
__global__ __launch_bounds__(512, 4) void seq_attn_mfma(
    const float* __restrict__ hidden,
    const unsigned short* __restrict__ wqt, const float* __restrict__ bq,
    const unsigned short* __restrict__ wkt, const float* __restrict__ bk,
    const unsigned short* __restrict__ wvt, const float* __restrict__ bv,
    const float* __restrict__ mask, unsigned short* __restrict__ ctx_all,
    unsigned short* __restrict__ Kf, unsigned short* __restrict__ Vf) {
  __shared__ __align__(16) unsigned short aT[32][264];
  __shared__ __align__(16) unsigned short kvb[32][272];
  __shared__ __align__(16) unsigned short qs16[2][264];
  __shared__ float pr[4][2][36];
  int a = blockIdx.x, t = threadIdx.x;
  int w = t >> 6, l = t & 63;                 // w in [0,8)
  int lm = l & 15, lkq = l >> 4, lk = lkq << 3;
  size_t hb = (size_t)a * (SEQ * E);
  #pragma unroll
  for (int i = 0; i < 4; ++i) {
    int p = i * 512 + t; int row = p >> 6, c4 = (p & 63) << 2;
    float4 v = *(const float4*)&hidden[hb + row * E + c4];
    *(s16x4*)&aT[row][c4] = f2bf4(v);
  }
  __syncthreads();
  bool isn0 = ((a & 63) == 0);
  int nb = a >> 6;
  f32x4 zz = {0.f, 0.f, 0.f, 0.f};
  // ---- K (all rows) + Q (rows 0,1): each wave handles 2 n-tiles of 16 cols ----
  #pragma unroll
  for (int nt = 0; nt < 2; ++nt) {
    int ncol = w * 32 + nt * 16 + lm;
    const unsigned short* bkrow = wkt + ((size_t)(w * 2 + nt) * 8) * 512 + l * 8;
    const unsigned short* bqrow = wqt + ((size_t)(w * 2 + nt) * 8) * 512 + l * 8;
    bf16x8 bk8[8], bq8[8];
    #pragma unroll
    for (int kc = 0; kc < 8; ++kc) bk8[kc] = *(const bf16x8*)(bkrow + kc * 512);
    #pragma unroll
    for (int kc = 0; kc < 8; ++kc) bq8[kc] = *(const bf16x8*)(bqrow + kc * 512);
    f32x4 ak0 = zz, ak1 = zz, aq = zz;
    #pragma unroll
    for (int kc = 0; kc < 8; ++kc) {
      bf16x8 a0 = *(const bf16x8*)&aT[lm][kc * 32 + lk];
      bf16x8 a1 = *(const bf16x8*)&aT[16 + lm][kc * 32 + lk];
      ak0 = mfma16(a0, bk8[kc], ak0);
      ak1 = mfma16(a1, bk8[kc], ak1);
      aq  = mfma16(a0, bq8[kc], aq);
    }
    float bb = bk[ncol];
    #pragma unroll
    for (int r = 0; r < 4; ++r) {
      int rw = (lkq << 2) + r;
      float v0 = ak0[r] + bb, v1 = ak1[r] + bb;
      kvb[rw][ncol] = f2bf(v0);
      kvb[16 + rw][ncol] = f2bf(v1);
      if (isn0) {
        Kf[((size_t)nb * 32 + rw) * 256 + ncol] = f2bf(v0);
        Kf[((size_t)nb * 32 + 16 + rw) * 256 + ncol] = f2bf(v1);
      }
    }
    if (lkq == 0) {
      float bqv = bq[ncol];
      qs16[0][ncol] = f2bf(aq[0] + bqv);
      qs16[1][ncol] = f2bf(aq[1] + bqv);
    }
  }
  __syncthreads();
  // ---- QK^T scores via MFMA (head = wave, waves 0-3 only), softmax in 16-lane group ----
  if (w < 4) {
    f32x4 sc0 = zz, sc1 = zz;
    #pragma unroll
    for (int kc2 = 0; kc2 < 2; ++kc2) {
      bf16x8 aq = *(const bf16x8*)&qs16[lm & 1][w * 64 + kc2 * 32 + lk];
      bf16x8 b0 = *(const bf16x8*)&kvb[lm][w * 64 + kc2 * 32 + lk];
      bf16x8 b1 = *(const bf16x8*)&kvb[16 + lm][w * 64 + kc2 * 32 + lk];
      sc0 = mfma16(aq, b0, sc0);
      sc1 = mfma16(aq, b1, sc1);
    }
    float mv0 = (lm < 4) ? NEG_MASK : mask[(size_t)a * SEQ + lm];
    float mv1 = mask[(size_t)a * SEQ + 16 + lm];
    #pragma unroll
    for (int r = 0; r < 2; ++r) {
      float s0 = sc0[r] * 0.125f + mv0;
      float s1 = sc1[r] * 0.125f + mv1;
      float mx = fmaxf(s0, s1);
      mx = fmaxf(mx, __shfl_xor(mx, 1));
      mx = fmaxf(mx, __shfl_xor(mx, 2));
      mx = fmaxf(mx, __shfl_xor(mx, 4));
      mx = fmaxf(mx, __shfl_xor(mx, 8));
      float e0 = expf(s0 - mx), e1 = expf(s1 - mx);
      float se = e0 + e1;
      se += __shfl_xor(se, 1); se += __shfl_xor(se, 2);
      se += __shfl_xor(se, 4); se += __shfl_xor(se, 8);
      float inv = 1.f / se;
      if (lkq == 0) {
        pr[w][r][lm] = e0 * inv;
        pr[w][r][16 + lm] = e1 * inv;
      }
    }
  }
  __syncthreads();
  // ---- V projection (each wave: 2 n-tiles), overwrites kvb ----
  #pragma unroll
  for (int nt = 0; nt < 2; ++nt) {
    int ncol = w * 32 + nt * 16 + lm;
    const unsigned short* bvrow = wvt + ((size_t)(w * 2 + nt) * 8) * 512 + l * 8;
    bf16x8 bv8[8];
    #pragma unroll
    for (int kc = 0; kc < 8; ++kc) bv8[kc] = *(const bf16x8*)(bvrow + kc * 512);
    f32x4 av0 = zz, av1 = zz;
    #pragma unroll
    for (int kc = 0; kc < 8; ++kc) {
      bf16x8 a0 = *(const bf16x8*)&aT[lm][kc * 32 + lk];
      bf16x8 a1 = *(const bf16x8*)&aT[16 + lm][kc * 32 + lk];
      av0 = mfma16(a0, bv8[kc], av0);
      av1 = mfma16(a1, bv8[kc], av1);
    }
    float bb = bv[ncol];
    #pragma unroll
    for (int r = 0; r < 4; ++r) {
      int rw = (lkq << 2) + r;
      float v0 = av0[r] + bb, v1 = av1[r] + bb;
      kvb[rw][ncol] = f2bf(v0);
      kvb[16 + rw][ncol] = f2bf(v1);
      if (isn0) {
        Vf[((size_t)nb * 32 + rw) * 256 + ncol] = f2bf(v0);
        Vf[((size_t)nb * 32 + 16 + rw) * 256 + ncol] = f2bf(v1);
      }
    }
  }
  __syncthreads();
  // ---- PV rows 0,1: threads 0-255 -> row 0, 256-511 -> row 1 ----
  {
    int col = t & 255;
    int qr = t >> 8;
    int hh = col >> 6;
    float o = 0.f;
    #pragma unroll
    for (int tt = 0; tt < 32; ++tt)
      o = fmaf(pr[hh][qr][tt], bf2f(kvb[tt][col]), o);
    ctx_all[((size_t)a * 2 + qr) * E + col] = f2bf(o);
  }
}

// ---------------- Q projection for n0 rows (gathered A), swizzled B ----------------
__global__ __launch_bounds__(256) void gemm_bias_kernel(
    const float* __restrict__ Af, const unsigned short* __restrict__ Bt,
    const float* __restrict__ bias, unsigned short* __restrict__ outb) {
  __shared__ __align__(16) unsigned short aT[32][264];
  int t = threadIdx.x, w = t >> 6, l = t & 63;
  int lm = l & 15, lkq = l >> 4, lk = lkq << 3;
  int row0 = blockIdx.x * 32;
  #pragma unroll
  for (int i = 0; i < 8; ++i) {
    int p = i * 256 + t; int row = p >> 6, c4 = (p & 63) << 2;
    int gr = row0 + row;
    int src = ((gr >> 5) << 11) + (gr & 31);
    float4 v = *(const float4*)&Af[(size_t)src * E + c4];
    *(s16x4*)&aT[row][c4] = f2bf4(v);
  }
  __syncthreads();
  f32x4 zz = {0.f, 0.f, 0.f, 0.f};
  #pragma unroll
  for (int nt = 0; nt < 4; ++nt) {
    int ncol = w * 64 + nt * 16 + lm;
    const unsigned short* brow = Bt + ((size_t)(w * 4 + nt) * 8) * 512 + l * 8;
    bf16x8 b8[8];
    #pragma unroll
    for (int kc = 0; kc < 8; ++kc) b8[kc] = *(const bf16x8*)(brow + kc * 512);
    f32x4 c0 = zz, c1 = zz;
    #pragma unroll
    for (int kc = 0; kc < 8; ++kc) {
      bf16x8 a0 = *(const bf16x8*)&aT[lm][kc * 32 + lk];
      bf16x8 a1 = *(const bf16x8*)&aT[16 + lm][kc * 32 + lk];
      c0 = mfma16(a0, b8[kc], c0);
      c1 = mfma16(a1, b8[kc], c1);
    }
    float bb = bias[ncol];
    #pragma unroll
    for (int r = 0; r < 4; ++r) {
      int rw = (lkq << 2) + r;
      outb[(size_t)(row0 + rw) * E + ncol] = f2bf(c0[r] + bb);
      outb[(size_t)(row0 + 16 + rw) * E + ncol] = f2bf(c1[r] + bb);
    }
  }
}

// ---------------- iter-1 QKV: grid (seq, matrix) ----------------
__global__ __launch_bounds__(256) void qkv1_kernel(
    const unsigned short* __restrict__ Ab,
    const unsigned short* __restrict__ wq, const float* __restrict__ bqv,
    const unsigned short* __restrict__ wk, const float* __restrict__ bkv,
    const unsigned short* __restrict__ wv, const float* __restrict__ bvv,
    unsigned short* q2, unsigned short* k2, unsigned short* v2) {
  __shared__ __align__(16) unsigned short aT[32][264];
  int t = threadIdx.x, w = t >> 6, l = t & 63;
  int lm = l & 15, lkq = l >> 4, lk = lkq << 3;
  int row0 = blockIdx.x * 32;
  int m = blockIdx.y;
  const unsigned short* Wt = (m == 0) ? wq : (m == 1) ? wk : wv;
  const float* bb = (m == 0) ? bqv : (m == 1) ? bkv : bvv;
  unsigned short* outb = (m == 0) ? q2 : (m == 1) ? k2 : v2;
  #pragma unroll
  for (int i = 0; i < 4; ++i) {
    int p = i * 256 + t; int row = p >> 5, c8 = (p & 31) << 3;
    *(s16x4*)&aT[row][c8] = *(const s16x4*)&Ab[(size_t)(row0 + row) * E + c8];
    *(s16x4*)&aT[row][c8 + 4] = *(const s16x4*)&Ab[(size_t)(row0 + row) * E + c8 + 4];
  }
  __syncthreads();
  f32x4 zz = {0.f, 0.f, 0.f, 0.f};
  #pragma unroll
  for (int nt = 0; nt < 4; ++nt) {
    int ncol = w * 64 + nt * 16 + lm;
    const unsigned short* brow = Wt + ((size_t)(w * 4 + nt) * 8) * 512 + l * 8;
    bf16x8 b8[8];
    #pragma unroll
    for (int kc = 0; kc < 8; ++kc) b8[kc] = *(const bf16x8*)(brow + kc * 512);
    f32x4 c0 = zz, c1 = zz;
    #pragma unroll
    for (int kc = 0; kc < 8; ++kc) {
      bf16x8 a0 = *(const bf16x8*)&aT[lm][kc * 32 + lk];
      bf16x8 a1 = *(const bf16x8*)&aT[16 + lm][kc * 32 + lk];
      c0 = mfma16(a0, b8[kc], c0);
      c1 = mfma16(a1, b8[kc], c1);
    }
    float bv2 = bb[ncol];
    #pragma unroll
    for (int r = 0; r < 4; ++r) {
      int rw = (lkq << 2) + r;
      outb[(size_t)(row0 + rw) * E + ncol] = f2bf(c0[r] + bv2);
      outb[(size_t)(row0 + 16 + rw) * E + ncol] = f2bf(c1[r] + bv2);
    }
  }
}

// ---------------- full attention (bf16 in/out), compact 64-seq buffers ----------------
__global__ __launch_bounds__(256) void attnf_kernel(
    const unsigned short* __restrict__ Q, const unsigned short* __restrict__ K,
    const unsigned short* __restrict__ V, unsigned short* __restrict__ CTX,
    const float* __restrict__ mask, int set4) {
  int b = blockIdx.x, h = blockIdx.y, t = threadIdx.x;
  __shared__ float qsh[32][65], ksh[32][65], vsh[32][65];
  __shared__ float pr[32][33];
  size_t base = (size_t)b * (SEQ * E) + h * 64;
  for (int i = 0; i < 8; ++i) {
    int p = i * 256 + t; int s = p >> 6, d = p & 63;
    qsh[s][d] = bf2f(Q[base + s * E + d]);
    ksh[s][d] = bf2f(K[base + s * E + d]);
    vsh[s][d] = bf2f(V[base + s * E + d]);
  }
  __syncthreads();
  for (int i = 0; i < 4; ++i) {
    int p = i * 256 + t; int s = p >> 5, tt = p & 31;
    float acc = 0.f;
    #pragma unroll
    for (int d = 0; d < 64; ++d) acc = fmaf(qsh[s][d], ksh[tt][d], acc);
    float mv = mask[(size_t)b * 2048 + tt];
    if (set4 && tt < 4) mv = NEG_MASK;
    pr[s][tt] = acc * 0.125f + mv;
  }
  __syncthreads();
  int rrow = t >> 3, l8 = t & 7;
  float vals[4];
  float mx = -1e30f;
  #pragma unroll
  for (int ii = 0; ii < 4; ++ii) { vals[ii] = pr[rrow][l8 + ii * 8]; mx = fmaxf(mx, vals[ii]); }
  mx = fmaxf(mx, __shfl_xor(mx, 1));
  mx = fmaxf(mx, __shfl_xor(mx, 2));
  mx = fmaxf(mx, __shfl_xor(mx, 4));
  float se = 0.f;
  #pragma unroll
  for (int ii = 0; ii < 4; ++ii) { vals[ii] = expf(vals[ii] - mx); se += vals[ii]; }
  se += __shfl_xor(se, 1); se += __shfl_xor(se, 2); se += __shfl_xor(se, 4);
  float inv = 1.f / se;
  #pragma unroll
  for (int ii = 0; ii < 4; ++ii) pr[rrow][l8 + ii * 8] = vals[ii] * inv;
  __syncthreads();
  for (int i = 0; i < 8; ++i) {
    int p = i * 256 + t; int s = p >> 6, d = p & 63;
    float acc = 0.f;
    #pragma unroll
    for (int tt = 0; tt < SEQ; ++tt) acc = fmaf(pr[s][tt], vsh[tt][d], acc);
    CTX[base + s * E + d] = f2bf(acc);
  }
}

__device__ __forceinline__ int map_res(int gr) {
  if (gr < 8192) return ((gr >> 1) << 5) + (gr & 1);
  int rr = gr - 8192;
  return ((rr >> 5) << 11) + (rr & 31);
}

// ---------------- tailA: Wo GEMM + LN1 -> a_bf (bf16) + a_f32 ----------------
__global__ __launch_bounds__(256) void tailA_mfma(
    const unsigned short* __restrict__ ctx,
    const unsigned short* __restrict__ wo, const float* __restrict__ bo,
    const float* __restrict__ Res, int resmode,
    const float* __restrict__ g1, const float* __restrict__ b1,
    unsigned short* __restrict__ a_bf, float* __restrict__ a_f32) {
  __shared__ __align__(16) unsigned short aT[32][264];
  __shared__ float sT[32][257];
  __shared__ float prs[32][4], prq[32][4];
  int t = threadIdx.x, w = t >> 6, l = t & 63;
  int row0 = blockIdx.x * 32;
  #pragma unroll
  for (int i = 0; i < 8; ++i) {
    int p = i * 256 + t; int row = p >> 6, c4 = (p & 63) << 2;
    *(s16x4*)&aT[row][c4] = *(const s16x4*)&ctx[(size_t)(row0 + row) * E + c4];
  }
  __syncthreads();
  {
    int lm = l & 15, lkq = l >> 4, lk = lkq << 3;
    f32x4 zz = {0.f, 0.f, 0.f, 0.f};
    #pragma unroll
    for (int nt = 0; nt < 4; ++nt) {
      int ncol = w * 64 + nt * 16 + lm;
      const unsigned short* brow = wo + ((size_t)(w * 4 + nt) * 8) * 512 + l * 8;
      bf16x8 b8[8];
      #pragma unroll
      for (int kc = 0; kc < 8; ++kc) b8[kc] = *(const bf16x8*)(brow + kc * 512);
      f32x4 c0 = zz, c1 = zz;
      #pragma unroll
      for (int kc = 0; kc < 8; ++kc) {
        bf16x8 a0 = *(const bf16x8*)&aT[lm][kc * 32 + lk];
        bf16x8 a1 = *(const bf16x8*)&aT[16 + lm][kc * 32 + lk];
        c0 = mfma16(a0, b8[kc], c0);
        c1 = mfma16(a1, b8[kc], c1);
      }
      float bb = bo[ncol];
      #pragma unroll
      for (int r = 0; r < 4; ++r) {
        int rw = (lkq << 2) + r;
        int rr0 = resmode ? map_res(row0 + rw) : (row0 + rw);
        int rr1 = resmode ? map_res(row0 + 16 + rw) : (row0 + 16 + rw);
        sT[rw][ncol] = c0[r] + bb + Res[(size_t)rr0 * E + ncol];
        sT[16 + rw][ncol] = c1[r] + bb + Res[(size_t)rr1 * E + ncol];
      }
    }
  }
  __syncthreads();
  {
    int wid = t >> 6, lane = t & 63;
    float vcache[32];
    for (int r = 0; r < 32; ++r) {
      float v = sT[r][t];
      vcache[r] = v;
      float s = v, q = v * v;
      #pragma unroll
      for (int o = 32; o > 0; o >>= 1) { s += __shfl_down(s, o); q += __shfl_down(q, o); }
      if (lane == 0) { prs[r][wid] = s; prq[r][wid] = q; }
    }
    __syncthreads();
    #pragma unroll
    for (int r = 0; r < 32; ++r) {
      float Sv = prs[r][0] + prs[r][1] + prs[r][2] + prs[r][3];
      float Qv = prq[r][0] + prq[r][1] + prq[r][2] + prq[r][3];
      float m = Sv * (1.f / E), var = Qv * (1.f / E) - m * m;
      float val = (vcache[r] - m) * rsqrtf(var + 1e-12f) * g1[t] + b1[t];
      a_f32[(size_t)(row0 + r) * E + t] = val;
      a_bf[(size_t)(row0 + r) * E + t] = f2bf(val);
    }
  }
}

// ---------------- ffnB: one FF-quarter GEMM1 + gelu + partial GEMM2 (512 thr); bf16 partials ----------------
__global__ __launch_bounds__(512) void ffnB_kernel(
    const unsigned short* __restrict__ a_bf,
    const unsigned short* __restrict__ wi, const float* __restrict__ bi,
    const unsigned short* __restrict__ wf,
    unsigned short* __restrict__ part, size_t pstride) {
  __shared__ __align__(16) unsigned short aT[32][264];
  __shared__ __align__(16) unsigned short fT[32][264];
  int t = threadIdx.x, w = t >> 6, l = t & 63;
  int lm = l & 31, lk = (l >> 5) << 3;
  int row0 = blockIdx.x * 32, qh = blockIdx.y;
  #pragma unroll
  for (int i = 0; i < 2; ++i) {
    int chunk = i * 512 + t; int row = chunk >> 5, c8 = (chunk & 31) << 3;
    *(s16x4*)&aT[row][c8] = *(const s16x4*)&a_bf[(size_t)(row0 + row) * E + c8];
    *(s16x4*)&aT[row][c8 + 4] = *(const s16x4*)&a_bf[(size_t)(row0 + row) * E + c8 + 4];
  }
  __syncthreads();
  f32x16 zz16 = {0};
  {
    const unsigned short* brow = wi + ((size_t)(qh * 8 + w) * 16) * 512 + l * 8;
    bf16x8 b16[16];
    #pragma unroll
    for (int kc = 0; kc < 16; ++kc) b16[kc] = *(const bf16x8*)(brow + kc * 512);
    f32x16 c = zz16;
    #pragma unroll
    for (int kc = 0; kc < 16; ++kc) {
      bf16x8 a = *(const bf16x8*)&aT[lm][kc * 16 + lk];
      c = mfma32(a, b16[kc], c);
    }
    int lcol = w * 32 + lm;
    float bib = bi[qh * 256 + lcol];
    #pragma unroll
    for (int reg = 0; reg < 16; ++reg) {
      int row = (reg & 3) + 8 * (reg >> 2) + 4 * (l >> 5);
      float x = c[reg] + bib;
      fT[row][lcol] = f2bf(0.5f * x * (1.f + erff(x * 0.70710678118654752f)));
    }
  }
  __syncthreads();
  {
    const unsigned short* brow = wf + ((size_t)(w * 64 + qh * 16)) * 512 + l * 8;
    bf16x8 b16[16];
    #pragma unroll
    for (int kc = 0; kc < 16; ++kc) b16[kc] = *(const bf16x8*)(brow + kc * 512);
    f32x16 c = zz16;
    #pragma unroll
    for (int kc = 0; kc < 16; ++kc) {
      bf16x8 a = *(const bf16x8*)&fT[lm][kc * 16 + lk];
      c = mfma32(a, b16[kc], c);
    }
    unsigned short* po = part + (size_t)qh * pstride;
    int col = w * 32 + lm;
    #pragma unroll
    for (int reg = 0; reg < 16; ++reg) {
      int row = (reg & 3) + 8 * (reg >> 2) + 4 * (l >> 5);
      po[(size_t)(row0 + row) * E + col] = f2bf(c[reg]);
    }
  }
}

// ---------------- ffnC: sum 4 bf16 partials + bias + residual + LN2 ----------------
__global__ __launch_bounds__(256) void ffnC_kernel(
    const unsigned short* __restrict__ part, size_t pstride,
    const float* __restrict__ bfv, const float* __restrict__ a_f32,
    const float* __restrict__ g2, const float* __restrict__ b2,
    float* __restrict__ out0, float* __restrict__ out1, int split) {
  __shared__ float prs[32][4], prq[32][4];
  int t = threadIdx.x;
  int row0 = blockIdx.x * 32;
  int wid = t >> 6, lane = t & 63;
  float bb = bfv[t];
  float vcache[32];
  for (int r = 0; r < 32; ++r) {
    size_t idx = (size_t)(row0 + r) * E + t;
    float v = bf2f(part[idx]) + bf2f(part[pstride + idx]) +
              bf2f(part[2 * pstride + idx]) + bf2f(part[3 * pstride + idx]) +
              bb + a_f32[idx];
    vcache[r] = v;
    float s = v, q = v * v;
    #pragma unroll
    for (int o = 32; o > 0; o >>= 1) { s += __shfl_down(s, o); q += __shfl_down(q, o); }
    if (lane == 0) { prs[r][wid] = s; prq[r][wid] = q; }
  }
  __syncthreads();
  #pragma unroll
  for (int r = 0; r < 32; ++r) {
    float Sv = prs[r][0] + prs[r][1] + prs[r][2] + prs[r][3];
    float Qv = prq[r][0] + prq[r][1] + prq[r][2] + prq[r][3];
    float m = Sv * (1.f / E), var = Qv * (1.f / E) - m * m;
    float val = (vcache[r] - m) * rsqrtf(var + 1e-12f) * g2[t] + b2[t];
    int gr = row0 + r;
    if (gr < split) out0[(size_t)gr * E + t] = val;
    else            out1[(size_t)(gr - split) * E + t] = val;
  }
}

// ---------------- fused agg (iter0) + build iter-1 input ----------------
__global__ __launch_bounds__(256) void agg_build_kernel(
    const float* __restrict__ h1n0,
    const float* __restrict__ p1, const float* __restrict__ p2,
    const float* __restrict__ Wagg, const float* __restrict__ bagg,
    const float* __restrict__ qe, const float* __restrict__ ke,
    const float* __restrict__ de, const float* __restrict__ ce,
    float* __restrict__ agg0,
    float* __restrict__ h2f, unsigned short* __restrict__ h2b) {
  __shared__ float pv[768];
  __shared__ float tmp4[4];
  int b = blockIdx.x, t = threadIdx.x;
  float x = h1n0[(size_t)b * (SEQ * E) + 4 * E + t];
  float n2 = block_sum256(x * x, tmp4);
  pv[t] = x / fmaxf(sqrtf(n2), 1e-12f);
  pv[256 + t] = p1[b * E + t];
  pv[512 + t] = p2[b * E + t];
  __syncthreads();
  float y = bagg[t];
  for (int u = 0; u < 768; ++u) y = fmaf(pv[u], Wagg[u * E + t], y);
  y = fmaxf(y, 0.f);
  float n3 = block_sum256(y * y, tmp4);
  float aggv = y / fmaxf(sqrtf(n3), 1e-12f);
  agg0[b * E + t] = aggv;
  size_t eb = (size_t)(b * 64) * E + t;
  size_t ob = (size_t)b * (SEQ * E);
  float v;
  v = qe[eb];  h2f[ob + 0 * E + t] = v; h2b[ob + 0 * E + t] = f2bf(v);
  v = ke[eb];  h2f[ob + 1 * E + t] = v; h2b[ob + 1 * E + t] = f2bf(v);
  v = de[eb];  h2f[ob + 2 * E + t] = v; h2b[ob + 2 * E + t] = f2bf(v);
  v = ce[eb];  h2f[ob + 3 * E + t] = v; h2b[ob + 3 * E + t] = f2bf(v);
  h2f[ob + 4 * E + t] = aggv; h2b[ob + 4 * E + t] = f2bf(aggv);
  for (int s = 5; s < SEQ; ++s) {
    v = h1n0[ob + s * E + t];
    h2f[ob + s * E + t] = v; h2b[ob + s * E + t] = f2bf(v);
  }
}

// ---------------- fused agg (iter1) + final output ----------------
__global__ __launch_bounds__(256) void agg_out_kernel(
    const float* __restrict__ h2,
    const float* __restrict__ p1, const float* __restrict__ p2,
    const float* __restrict__ Wagg, const float* __restrict__ bagg,
    const float* __restrict__ h1n0, const float* __restrict__ agg0,
    float* __restrict__ outp) {
  __shared__ float pv[768];
  __shared__ float tmp4[4];
  int b = blockIdx.x, t = threadIdx.x;
  float x = h2[(size_t)b * (SEQ * E) + 4 * E + t];
  float n2 = block_sum256(x * x, tmp4);
  pv[t] = x / fmaxf(sqrtf(n2), 1e-12f);
  pv[256 + t] = p1[b * E + t];
  pv[512 + t] = p2[b * E + t];
  __syncthreads();
  float y = bagg[t];
  for (int u = 0; u < 768; ++u) y = fmaf(pv[u], Wagg[u * E + t], y);
  y = fmaxf(y, 0.f);
  float n3 = block_sum256(y * y, tmp4);
  float agg1v = y / fmaxf(sqrtf(n3), 1e-12f);
  size_t ob = (size_t)b * (SEQ * E);
  float s1v = agg0[b * E + t];
  float s2v = agg1v;
  for (int s = 5; s < SEQ; ++s) { s1v += h1n0[ob + s * E + t]; s2v += h2[ob + s * E + t]; }
  outp[b * E + t] = 0.5f * (s1v + s2v) * (1.f / 28.f);
}

extern "C" void kernel_launch(void* const* d_in, const int* in_sizes, int n_in,
                              void* d_out, int out_size, void* d_ws, size_t ws_size,
                              hipStream_t stream) {
  (void)in_sizes; (void)n_in; (void)out_size;
  const float* hidden = (const float*)d_in[1];
  const float* amask  = (const float*)d_in[2];
  const float* qemb   = (const float*)d_in[3];
  const float* kemb   = (const float*)d_in[4];
  const float* demb   = (const float*)d_in[5];
  const float* cemb   = (const float*)d_in[6];
  const float* uop    = (const float*)d_in[7];
  const float* iop    = (const float*)d_in[8];
  const float* Wq = (const float*)d_in[9];  const float* bq = (const float*)d_in[10];
  const float* Wk = (const float*)d_in[11]; const float* bk = (const float*)d_in[12];
  const float* Wv = (const float*)d_in[13]; const float* bv = (const float*)d_in[14];
  const float* Wo = (const float*)d_in[15]; const float* bo = (const float*)d_in[16];
  const float* g1 = (const float*)d_in[17]; const float* b1 = (const float*)d_in[18];
  const float* Wi = (const float*)d_in[19]; const float* bi = (const float*)d_in[20];
  const float* Wf = (const float*)d_in[21]; const float* bf = (const float*)d_in[22];
  const float* g2 = (const float*)d_in[23]; const float* b2 = (const float*)d_in[24];
  const float* Wagg = (const float*)d_in[25]; const float* bagg = (const float*)d_in[26];
  const float* Wd1 = (const float*)d_in[27]; const float* bd1 = (const float*)d_in[28];
  const float* l1g = (const float*)d_in[29]; const float* l1b = (const float*)d_in[30];
  const float* Wd2 = (const float*)d_in[31]; const float* bd2 = (const float*)d_in[32];
  const float* l2g = (const float*)d_in[33]; const float* l2b = (const float*)d_in[34];

  // ---- workspace carve ----
  char* cur = (char*)d_ws;
  auto alloc_us = [&](size_t n) { unsigned short* p = (unsigned short*)cur; cur += ((n * 2 + 255) & ~(size_t)255); return p; };
  auto alloc_f  = [&](size_t n) { float* p = (float*)cur; cur += ((n * 4 + 255) & ~(size_t)255); return p; };
  unsigned short* wqt = alloc_us(131072);
  unsigned short* wkt = alloc_us(131072);
  unsigned short* wvt = alloc_us(131072);
  unsigned short* wot = alloc_us(131072);
  unsigned short* wit = alloc_us(524288);
  unsigned short* wft = alloc_us(524288);
  unsigned short* ctx_all = alloc_us((size_t)10240 * 256);
  unsigned short* qn0 = alloc_us((size_t)2048 * 256);
  unsigned short* Kf  = alloc_us((size_t)2048 * 256);
  unsigned short* Vf  = alloc_us((size_t)2048 * 256);
  unsigned short* h2inb = alloc_us((size_t)2048 * 256);
  unsigned short* a_bf = alloc_us((size_t)10240 * 256);
  unsigned short* q2b = alloc_us((size_t)2048 * 256);
  unsigned short* k2b = alloc_us((size_t)2048 * 256);
  unsigned short* v2b = alloc_us((size_t)2048 * 256);
  unsigned short* ctx1 = alloc_us((size_t)2048 * 256);
  unsigned short* part = alloc_us((size_t)4 * 10240 * 256);
  float* a_f32 = alloc_f((size_t)10240 * 256);
  float* h101  = alloc_f((size_t)4096 * 2 * 256);
  float* h1n0  = alloc_f((size_t)2048 * 256);
  float* h2inf = alloc_f((size_t)2048 * 256);
  float* h2    = alloc_f((size_t)2048 * 256);
  float* p1_0  = alloc_f(64 * 256);
  float* p2_0  = alloc_f(64 * 256);
  float* p1_1  = alloc_f(64 * 256);
  float* p2_1  = alloc_f(64 * 256);
  float* agg0  = alloc_f(64 * 256);
  if ((size_t)(cur - (char*)d_ws) > ws_size) return;
  const size_t PSTRIDE = (size_t)10240 * 256;

  // ---- weight prep (fragment-order swizzle) ----
  wprep_kernel<<<dim3(128, 6, 2), 256, 0, stream>>>(Wq, Wk, Wv, Wo, Wi, Wf,
                                                    wqt, wkt, wvt, wot, wit, wft);

  // ================= iteration 0 =================
  prop_ln_kernel<<<dim3(64, 2), 256, 0, stream>>>(qemb, kemb, nullptr, uop, iop,
                                                  Wd1, bd1, l1g, l1b, Wd2, bd2, l2g, l2b,
                                                  p1_0, p2_0);
  seq_attn_mfma<<<4096, 512, 0, stream>>>(hidden, wqt, bq, wkt, bk, wvt, bv,
                                          amask, ctx_all, Kf, Vf);
  gemm_bias_kernel<<<64, 256, 0, stream>>>(hidden, wqt, bq, qn0);
  attnf_kernel<<<dim3(64, 4), 256, 0, stream>>>(qn0, Kf, Vf, ctx_all + (size_t)8192 * 256,
                                                amask, 1);
  tailA_mfma<<<320, 256, 0, stream>>>(ctx_all, wot, bo, hidden, 1, g1, b1, a_bf, a_f32);
  ffnB_kernel<<<dim3(320, 4), 512, 0, stream>>>(a_bf, wit, bi, wft, part, PSTRIDE);
  ffnC_kernel<<<320, 256, 0, stream>>>(part, PSTRIDE, bf, a_f32, g2, b2,
                                       h101, h1n0, 8192);
  agg_build_kernel<<<64, 256, 0, stream>>>(h1n0, p1_0, p2_0, Wagg, bagg,
                                           qemb, kemb, demb, cemb, agg0, h2inf, h2inb);

  // ================= iteration 1 =================
  prop_ln_kernel<<<dim3(64, 2), 256, 0, stream>>>(qemb, kemb, h101, uop, iop,
                                                  Wd1, bd1, l1g, l1b, Wd2, bd2, l2g, l2b,
                                                  p1_1, p2_1);
  qkv1_kernel<<<dim3(64, 3), 256, 0, stream>>>(h2inb,
                                               wqt + 65536, bq + E,
                                               wkt + 65536, bk + E,
                                               wvt + 65536, bv + E,
                                               q2b, k2b, v2b);
  attnf_kernel<<<dim3(64, 4), 256, 0, stream>>>(q2b, k2b, v2b, ctx1, amask, 0);
  tailA_mfma<<<64, 256, 0, stream>>>(ctx1, wot + 65536, bo + E, h2inf, 0,
                                     g1 + E, b1 + E, a_bf, a_f32);
  ffnB_kernel<<<dim3(64, 4), 512, 0, stream>>>(a_bf, wit + 262144, bi + FF,
                                               wft + 262144, part, PSTRIDE);
  ffnC_kernel<<<64, 256, 0, stream>>>(part, PSTRIDE, bf + E, a_f32,
                                      g2 + E, b2 + E, h2, h2, 1 << 30);
  agg_out_kernel<<<64, 256, 0, stream>>>(h2, p1_1, p2_1,
                                         Wagg + (size_t)768 * E, bagg + E,
                                         h1n0, agg0, (float*)d_out);
}